// Round 1
// baseline (2814.778 us; speedup 1.0000x reference)
//
#include <hip/hip_runtime.h>

#define BB 4
#define NN 16384
#define MM 512
#define CCH 256
#define KNN 24
#define EPSV 1e-5f

// ---------------- K0: transpose fc_w (256x256) -> Wt[cin][cout] ----------------
__global__ __launch_bounds__(256) void k_wt(const float* __restrict__ W, float* __restrict__ Wt) {
    int i = blockIdx.x * 256 + threadIdx.x;   // 65536
    int co = i >> 8, ci = i & 255;
    Wt[(ci << 8) + co] = W[i];
}

// ---------------- K1: top-24 nearest anchors per node ----------------
__global__ __launch_bounds__(128) void k_topk(const float* __restrict__ coords,
                                              const float* __restrict__ anchors,
                                              int* __restrict__ idx_out,
                                              int* __restrict__ deg) {
    __shared__ float ax[MM], ay[MM], az[MM], am2[MM];
    __shared__ float dl[KNN * 128];
    __shared__ int   il[KNN * 128];
    int tid = threadIdx.x;
    int blk = blockIdx.x;           // 512 blocks: 128 per batch
    int b = blk >> 7;
    int n0 = (blk & 127) << 7;

    for (int m = tid; m < MM; m += 128) {
        float x_ = anchors[(b * MM + m) * 3 + 0];
        float y_ = anchors[(b * MM + m) * 3 + 1];
        float z_ = anchors[(b * MM + m) * 3 + 2];
        ax[m] = x_; ay[m] = y_; az[m] = z_;
        am2[m] = x_ * x_ + y_ * y_ + z_ * z_;
    }
    #pragma unroll
    for (int j = 0; j < KNN; ++j) dl[j * 128 + tid] = 3.4e38f;
    __syncthreads();

    int n = n0 + tid;
    float cx = coords[(b * NN + n) * 3 + 0];
    float cy = coords[(b * NN + n) * 3 + 1];
    float cz = coords[(b * NN + n) * 3 + 2];
    float cn2 = cx * cx + cy * cy + cz * cz;

    float worst = 3.4e38f;
    for (int m = 0; m < MM; ++m) {
        float d2 = cn2 + am2[m] - 2.0f * (cx * ax[m] + cy * ay[m] + cz * az[m]);
        if (d2 < worst) {       // strict: ties keep earlier index (matches top_k)
            int j = KNN - 1;
            while (j > 0 && dl[(j - 1) * 128 + tid] > d2) {
                dl[j * 128 + tid] = dl[(j - 1) * 128 + tid];
                il[j * 128 + tid] = il[(j - 1) * 128 + tid];
                --j;
            }
            dl[j * 128 + tid] = d2;
            il[j * 128 + tid] = m;
            worst = dl[(KNN - 1) * 128 + tid];
        }
    }

    #pragma unroll
    for (int j = 0; j < KNN; ++j)
        atomicAdd(&deg[b * MM + il[j * 128 + tid]], 1);
    __syncthreads();
    // coalesced transposed write of indices
    int base = (b * NN + n0) * KNN;
    for (int q = tid; q < 128 * KNN; q += 128) {
        int nl = q / KNN, j = q % KNN;
        idx_out[base + q] = il[j * 128 + nl];
    }
}

// ---------------- K2: S = H^T x  (LDS-privatized scatter) ----------------
__global__ __launch_bounds__(256) void k_scatter(const float* __restrict__ x,
                                                 const int* __restrict__ idxb,
                                                 float* __restrict__ spart) {
    __shared__ float sloc[MM * 32];     // 64 KB
    int tid = threadIdx.x;
    int blk = blockIdx.x;               // 256 = b(4) * cc(8) * nc(8)
    int b  = blk >> 6;
    int cc = (blk >> 3) & 7;
    int nc = blk & 7;
    int c0 = cc << 5;
    int n0 = nc << 11;                  // *2048

    for (int i = tid; i < MM * 32; i += 256) sloc[i] = 0.0f;
    __syncthreads();

    int ch  = tid & 31;
    int sub = tid >> 5;                 // 0..7
    for (int g = 0; g < 256; ++g) {
        int n = n0 + (g << 3) + sub;
        float v = x[((b * NN + n) << 8) + c0 + ch];
        int myidx = 0;
        if (ch < KNN) myidx = idxb[(b * NN + n) * KNN + ch];
        #pragma unroll
        for (int k = 0; k < KNN; ++k) {
            int m = __shfl(myidx, k, 32);
            atomicAdd(&sloc[(m << 5) + ch], v);
        }
    }
    __syncthreads();
    float* dst = spart + ((((b * 8 + cc) * 8 + nc) * MM) << 5);
    for (int i = tid; i < MM * 32; i += 256) dst[i] = sloc[i];
}

// ---------------- K3: E' = ((S*inv_e)@W^T + b*(deg>0)) / 24 ----------------
__global__ __launch_bounds__(256) void k_edge(const float* __restrict__ spart,
                                              const int* __restrict__ deg,
                                              const float* __restrict__ Wt,
                                              const float* __restrict__ fcb,
                                              float* __restrict__ Ep) {
    __shared__ float srow[CCH];
    int tid = threadIdx.x;
    int blk = blockIdx.x;               // 2048 = b*MM + m
    int b = blk >> 9;
    int m = blk & 511;
    int d = deg[blk];
    float inv = (d > 0) ? (1.0f / (float)d) : 0.0f;

    int cc = tid >> 5, ch = tid & 31;
    float s = 0.0f;
    #pragma unroll
    for (int nc = 0; nc < 8; ++nc)
        s += spart[((((b * 8 + cc) * 8 + nc) * MM + m) << 5) + ch];
    srow[tid] = s * inv;
    __syncthreads();

    float a0 = (d > 0) ? fcb[tid] : 0.0f;
    float a1 = 0.f, a2 = 0.f, a3 = 0.f;
    #pragma unroll 4
    for (int ci = 0; ci < CCH; ci += 4) {
        a0 = fmaf(srow[ci + 0], Wt[((ci + 0) << 8) + tid], a0);
        a1 = fmaf(srow[ci + 1], Wt[((ci + 1) << 8) + tid], a1);
        a2 = fmaf(srow[ci + 2], Wt[((ci + 2) << 8) + tid], a2);
        a3 = fmaf(srow[ci + 3], Wt[((ci + 3) << 8) + tid], a3);
    }
    Ep[(blk << 8) + tid] = ((a0 + a1) + (a2 + a3)) * (1.0f / 24.0f);
}

// ---------------- K4: out = H@E' + x, transposed write + BN partials ----------------
#define NODES4 32
__global__ __launch_bounds__(256) void k_gather(const float* __restrict__ x,
                                                const int* __restrict__ idxb,
                                                const float* __restrict__ Ep,
                                                float* __restrict__ out,
                                                float* __restrict__ bn1,
                                                float* __restrict__ bn2) {
    __shared__ int   it[NODES4 * KNN];          // 768 ints
    __shared__ float tile[CCH][NODES4 + 1];     // 33.8 KB
    int tid = threadIdx.x;
    int blk = blockIdx.x;                       // 2048: b * 512 node-chunks
    int b = blk >> 9;
    int n0 = (blk & 511) * NODES4;

    for (int i = tid; i < NODES4 * KNN; i += 256)
        it[i] = idxb[(b * NN + n0) * KNN + i];
    __syncthreads();

    const float* Eb = Ep + ((b * MM) << 8);
    float sum = 0.0f, ss = 0.0f;
    for (int j = 0; j < NODES4; ++j) {
        int n = n0 + j;
        float a0 = 0.f, a1 = 0.f, a2 = 0.f, a3 = 0.f;
        #pragma unroll
        for (int k = 0; k < KNN; k += 4) {
            a0 += Eb[(it[j * KNN + k + 0] << 8) + tid];
            a1 += Eb[(it[j * KNN + k + 1] << 8) + tid];
            a2 += Eb[(it[j * KNN + k + 2] << 8) + tid];
            a3 += Eb[(it[j * KNN + k + 3] << 8) + tid];
        }
        float o = x[((b * NN + n) << 8) + tid] + ((a0 + a1) + (a2 + a3));
        tile[tid][j] = o;
        sum += o; ss += o * o;
    }
    bn1[tid * 2048 + blk] = sum;
    bn2[tid * 2048 + blk] = ss;
    __syncthreads();
    // dump transposed: out[b][c][n0 + j]
    for (int i = tid; i < CCH * NODES4; i += 256) {
        int c2 = i >> 5;
        int j2 = i & 31;
        out[((b * CCH + c2) << 14) + n0 + j2] = tile[c2][j2];
    }
}

// ---------------- K5: finalize BN stats -> a[c], bb[c] ----------------
__global__ __launch_bounds__(256) void k_stats(const float* __restrict__ bn1,
                                               const float* __restrict__ bn2,
                                               const float* __restrict__ gamma,
                                               const float* __restrict__ beta,
                                               float* __restrict__ ab) {
    __shared__ float r1[256], r2[256];
    int c = blockIdx.x;
    int t = threadIdx.x;
    float s1 = 0.f, s2 = 0.f;
    for (int i = t; i < 2048; i += 256) {
        s1 += bn1[c * 2048 + i];
        s2 += bn2[c * 2048 + i];
    }
    r1[t] = s1; r2[t] = s2;
    __syncthreads();
    for (int o = 128; o > 0; o >>= 1) {
        if (t < o) { r1[t] += r1[t + o]; r2[t] += r2[t + o]; }
        __syncthreads();
    }
    if (t == 0) {
        float mean = r1[0] * (1.0f / 65536.0f);
        float var  = r2[0] * (1.0f / 65536.0f) - mean * mean;
        float istd = rsqrtf(var + EPSV);
        float a = gamma[c] * istd;
        ab[c] = a;
        ab[CCH + c] = beta[c] - mean * a;
    }
}

// ---------------- K6: in-place normalize + SiLU ----------------
__global__ __launch_bounds__(256) void k_silu(float* __restrict__ out,
                                              const float* __restrict__ ab) {
    int i = blockIdx.x * 256 + threadIdx.x;     // float4 index, 4194304 total
    int c = (i >> 12) & 255;                    // 4096 float4 per (b,c) row
    float a = ab[c], bb = ab[CCH + c];
    float4 v = ((float4*)out)[i];
    float t0 = a * v.x + bb;
    float t1 = a * v.y + bb;
    float t2 = a * v.z + bb;
    float t3 = a * v.w + bb;
    v.x = t0 / (1.0f + __expf(-t0));
    v.y = t1 / (1.0f + __expf(-t1));
    v.z = t2 / (1.0f + __expf(-t2));
    v.w = t3 / (1.0f + __expf(-t3));
    ((float4*)out)[i] = v;
}

extern "C" void kernel_launch(void* const* d_in, const int* in_sizes, int n_in,
                              void* d_out, int out_size, void* d_ws, size_t ws_size,
                              hipStream_t stream) {
    (void)in_sizes; (void)n_in; (void)out_size; (void)ws_size;
    const float* x       = (const float*)d_in[0];
    const float* coords  = (const float*)d_in[1];
    const float* anchors = (const float*)d_in[2];
    const float* fcw     = (const float*)d_in[3];
    const float* fcb     = (const float*)d_in[4];
    const float* gamma   = (const float*)d_in[5];
    const float* beta    = (const float*)d_in[6];
    float* out = (float*)d_out;

    char* ws = (char*)d_ws;
    int*   ws_idx   = (int*)  (ws + 0);          // 6,291,456 B
    int*   ws_deg   = (int*)  (ws + 6291456);    // 8,192 B
    float* ws_spart = (float*)(ws + 6299648);    // 16,777,216 B
    float* ws_ep    = (float*)(ws + 23076864);   // 2,097,152 B
    float* ws_wt    = (float*)(ws + 25174016);   // 262,144 B
    float* ws_bn1   = (float*)(ws + 25436160);   // 2,097,152 B
    float* ws_bn2   = (float*)(ws + 27533312);   // 2,097,152 B
    float* ws_ab    = (float*)(ws + 29630464);   // 2,048 B

    hipMemsetAsync(ws_deg, 0, BB * MM * sizeof(int), stream);

    hipLaunchKernelGGL(k_wt,      dim3(256),   dim3(256), 0, stream, fcw, ws_wt);
    hipLaunchKernelGGL(k_topk,    dim3(512),   dim3(128), 0, stream, coords, anchors, ws_idx, ws_deg);
    hipLaunchKernelGGL(k_scatter, dim3(256),   dim3(256), 0, stream, x, ws_idx, ws_spart);
    hipLaunchKernelGGL(k_edge,    dim3(2048),  dim3(256), 0, stream, ws_spart, ws_deg, ws_wt, fcb, ws_ep);
    hipLaunchKernelGGL(k_gather,  dim3(2048),  dim3(256), 0, stream, x, ws_idx, ws_ep, out, ws_bn1, ws_bn2);
    hipLaunchKernelGGL(k_stats,   dim3(256),   dim3(256), 0, stream, ws_bn1, ws_bn2, gamma, beta, ws_ab);
    hipLaunchKernelGGL(k_silu,    dim3(16384), dim3(256), 0, stream, out, ws_ab);
}

// Round 2
// 1114.323 us; speedup vs baseline: 2.5260x; 2.5260x over previous
//
#include <hip/hip_runtime.h>

#define BB 4
#define NN 16384
#define MM 512
#define CCH 256
#define KNN 24
#define EPSV 1e-5f

// ---------------- K0: transpose fc_w (256x256) -> Wt[cin][cout] ----------------
__global__ __launch_bounds__(256) void k_wt(const float* __restrict__ W, float* __restrict__ Wt) {
    int i = blockIdx.x * 256 + threadIdx.x;   // 65536
    int co = i >> 8, ci = i & 255;
    Wt[(ci << 8) + co] = W[i];
}

// ---------------- K1: top-24 nearest anchors per node ----------------
__global__ __launch_bounds__(128) void k_topk(const float* __restrict__ coords,
                                              const float* __restrict__ anchors,
                                              int* __restrict__ idx_out,
                                              int* __restrict__ deg) {
    __shared__ float ax[MM], ay[MM], az[MM], am2[MM];
    __shared__ float dl[KNN * 128];
    __shared__ int   il[KNN * 128];
    int tid = threadIdx.x;
    int blk = blockIdx.x;           // 512 blocks: 128 per batch
    int b = blk >> 7;
    int n0 = (blk & 127) << 7;

    for (int m = tid; m < MM; m += 128) {
        float x_ = anchors[(b * MM + m) * 3 + 0];
        float y_ = anchors[(b * MM + m) * 3 + 1];
        float z_ = anchors[(b * MM + m) * 3 + 2];
        ax[m] = x_; ay[m] = y_; az[m] = z_;
        am2[m] = x_ * x_ + y_ * y_ + z_ * z_;
    }
    #pragma unroll
    for (int j = 0; j < KNN; ++j) dl[j * 128 + tid] = 3.4e38f;
    __syncthreads();

    int n = n0 + tid;
    float cx = coords[(b * NN + n) * 3 + 0];
    float cy = coords[(b * NN + n) * 3 + 1];
    float cz = coords[(b * NN + n) * 3 + 2];
    float cn2 = cx * cx + cy * cy + cz * cz;

    float worst = 3.4e38f;
    for (int m = 0; m < MM; ++m) {
        float d2 = cn2 + am2[m] - 2.0f * (cx * ax[m] + cy * ay[m] + cz * az[m]);
        if (d2 < worst) {       // strict: ties keep earlier index (matches top_k)
            int j = KNN - 1;
            while (j > 0 && dl[(j - 1) * 128 + tid] > d2) {
                dl[j * 128 + tid] = dl[(j - 1) * 128 + tid];
                il[j * 128 + tid] = il[(j - 1) * 128 + tid];
                --j;
            }
            dl[j * 128 + tid] = d2;
            il[j * 128 + tid] = m;
            worst = dl[(KNN - 1) * 128 + tid];
        }
    }

    #pragma unroll
    for (int j = 0; j < KNN; ++j)
        atomicAdd(&deg[b * MM + il[j * 128 + tid]], 1);
    __syncthreads();
    // coalesced transposed write of indices
    int base = (b * NN + n0) * KNN;
    for (int q = tid; q < 128 * KNN; q += 128) {
        int nl = q / KNN, j = q % KNN;
        idx_out[base + q] = il[j * 128 + nl];
    }
}

// ---------------- K2a: exclusive prefix sum of deg (2048) -> offs ----------------
__global__ __launch_bounds__(256) void k_offsets(const int* __restrict__ deg,
                                                 int* __restrict__ offs) {
    __shared__ int part[256];
    int t = threadIdx.x;
    int v[8];
    int s = 0;
    #pragma unroll
    for (int j = 0; j < 8; ++j) { v[j] = deg[t * 8 + j]; s += v[j]; }
    part[t] = s;
    __syncthreads();
    for (int off = 1; off < 256; off <<= 1) {
        int val = (t >= off) ? part[t - off] : 0;
        __syncthreads();
        part[t] += val;
        __syncthreads();
    }
    int excl = part[t] - s;
    #pragma unroll
    for (int j = 0; j < 8; ++j) { offs[t * 8 + j] = excl; excl += v[j]; }
}

// ---------------- K2b: fill CSR member lists (node ids per edge) ----------------
__global__ __launch_bounds__(256) void k_fill(const int* __restrict__ idxb,
                                              const int* __restrict__ offs,
                                              int* __restrict__ cur,
                                              int* __restrict__ list) {
    int gn = blockIdx.x * 256 + threadIdx.x;   // 0..65535
    int b = gn >> 14;
    #pragma unroll
    for (int k = 0; k < KNN; ++k) {
        int m = idxb[gn * KNN + k];
        int e = (b << 9) + m;
        int p = atomicAdd(&cur[e], 1);
        list[offs[e] + p] = gn & 16383;
    }
}

// ---------------- K3: E' = ((gather(x)*inv_e)@W^T + b*(deg>0)) / 24 ----------------
__global__ __launch_bounds__(256) void k_edge2(const float* __restrict__ x,
                                               const int* __restrict__ list,
                                               const int* __restrict__ offs,
                                               const int* __restrict__ deg,
                                               const float* __restrict__ Wt,
                                               const float* __restrict__ fcb,
                                               float* __restrict__ Ep) {
    __shared__ int nl[256];
    __shared__ float srow[CCH];
    int tid = threadIdx.x;
    int blk = blockIdx.x;     // b*512 + m
    int b = blk >> 9;
    int d = deg[blk];
    int o = offs[blk];
    const float* xb = x + ((size_t)b << 22);   // b * NN * CCH

    float a0 = 0.f, a1 = 0.f, a2 = 0.f, a3 = 0.f;
    for (int base = 0; base < d; base += 256) {
        int cnt = min(256, d - base);
        if (tid < cnt) nl[tid] = list[o + base + tid];
        __syncthreads();
        int i = 0;
        for (; i + 3 < cnt; i += 4) {
            const float* p0 = xb + (nl[i + 0] << 8);
            const float* p1 = xb + (nl[i + 1] << 8);
            const float* p2 = xb + (nl[i + 2] << 8);
            const float* p3 = xb + (nl[i + 3] << 8);
            a0 += p0[tid]; a1 += p1[tid]; a2 += p2[tid]; a3 += p3[tid];
        }
        for (; i < cnt; ++i) a0 += xb[(nl[i] << 8) + tid];
        __syncthreads();
    }
    float inv = (d > 0) ? (1.0f / (float)d) : 0.0f;
    srow[tid] = ((a0 + a1) + (a2 + a3)) * inv;
    __syncthreads();

    float c0 = (d > 0) ? fcb[tid] : 0.0f;
    float c1 = 0.f, c2 = 0.f, c3 = 0.f;
    #pragma unroll 4
    for (int ci = 0; ci < CCH; ci += 4) {
        c0 = fmaf(srow[ci + 0], Wt[((ci + 0) << 8) + tid], c0);
        c1 = fmaf(srow[ci + 1], Wt[((ci + 1) << 8) + tid], c1);
        c2 = fmaf(srow[ci + 2], Wt[((ci + 2) << 8) + tid], c2);
        c3 = fmaf(srow[ci + 3], Wt[((ci + 3) << 8) + tid], c3);
    }
    Ep[(blk << 8) + tid] = ((c0 + c1) + (c2 + c3)) * (1.0f / 24.0f);
}

// ---------------- K4: out = H@E' + x, transposed write + BN partials ----------------
#define NODES4 32
__global__ __launch_bounds__(256) void k_gather(const float* __restrict__ x,
                                                const int* __restrict__ idxb,
                                                const float* __restrict__ Ep,
                                                float* __restrict__ out,
                                                float* __restrict__ bn1,
                                                float* __restrict__ bn2) {
    __shared__ int   it[NODES4 * KNN];          // 768 ints
    __shared__ float tile[CCH][NODES4 + 1];     // 33.8 KB
    int tid = threadIdx.x;
    int blk = blockIdx.x;                       // 2048: b * 512 node-chunks
    int b = blk >> 9;
    int n0 = (blk & 511) * NODES4;

    for (int i = tid; i < NODES4 * KNN; i += 256)
        it[i] = idxb[(b * NN + n0) * KNN + i];
    __syncthreads();

    const float* Eb = Ep + ((b * MM) << 8);
    float sum = 0.0f, ss = 0.0f;
    for (int j = 0; j < NODES4; ++j) {
        int n = n0 + j;
        float a0 = 0.f, a1 = 0.f, a2 = 0.f, a3 = 0.f;
        #pragma unroll
        for (int k = 0; k < KNN; k += 4) {
            a0 += Eb[(it[j * KNN + k + 0] << 8) + tid];
            a1 += Eb[(it[j * KNN + k + 1] << 8) + tid];
            a2 += Eb[(it[j * KNN + k + 2] << 8) + tid];
            a3 += Eb[(it[j * KNN + k + 3] << 8) + tid];
        }
        float o = x[((b * NN + n) << 8) + tid] + ((a0 + a1) + (a2 + a3));
        tile[tid][j] = o;
        sum += o; ss += o * o;
    }
    bn1[blk * 256 + tid] = sum;                 // coalesced
    bn2[blk * 256 + tid] = ss;
    __syncthreads();
    // dump transposed: out[b][c][n0 + j]
    for (int i = tid; i < CCH * NODES4; i += 256) {
        int c2 = i >> 5;
        int j2 = i & 31;
        out[((b * CCH + c2) << 14) + n0 + j2] = tile[c2][j2];
    }
}

// ---------------- K5: finalize BN stats -> a[c], bb[c] ----------------
__global__ __launch_bounds__(256) void k_stats(const float* __restrict__ bn1,
                                               const float* __restrict__ bn2,
                                               const float* __restrict__ gamma,
                                               const float* __restrict__ beta,
                                               float* __restrict__ ab) {
    __shared__ float r1[256], r2[256];
    int c = blockIdx.x;
    int t = threadIdx.x;
    float s1 = 0.f, s2 = 0.f;
    for (int i = t; i < 2048; i += 256) {
        s1 += bn1[i * 256 + c];
        s2 += bn2[i * 256 + c];
    }
    r1[t] = s1; r2[t] = s2;
    __syncthreads();
    for (int o = 128; o > 0; o >>= 1) {
        if (t < o) { r1[t] += r1[t + o]; r2[t] += r2[t + o]; }
        __syncthreads();
    }
    if (t == 0) {
        float mean = r1[0] * (1.0f / 65536.0f);
        float var  = r2[0] * (1.0f / 65536.0f) - mean * mean;
        float istd = rsqrtf(var + EPSV);
        float a = gamma[c] * istd;
        ab[c] = a;
        ab[CCH + c] = beta[c] - mean * a;
    }
}

// ---------------- K6: in-place normalize + SiLU ----------------
__global__ __launch_bounds__(256) void k_silu(float* __restrict__ out,
                                              const float* __restrict__ ab) {
    int i = blockIdx.x * 256 + threadIdx.x;     // float4 index, 4194304 total
    int c = (i >> 12) & 255;                    // 4096 float4 per (b,c) row
    float a = ab[c], bb = ab[CCH + c];
    float4 v = ((float4*)out)[i];
    float t0 = a * v.x + bb;
    float t1 = a * v.y + bb;
    float t2 = a * v.z + bb;
    float t3 = a * v.w + bb;
    v.x = t0 / (1.0f + __expf(-t0));
    v.y = t1 / (1.0f + __expf(-t1));
    v.z = t2 / (1.0f + __expf(-t2));
    v.w = t3 / (1.0f + __expf(-t3));
    ((float4*)out)[i] = v;
}

extern "C" void kernel_launch(void* const* d_in, const int* in_sizes, int n_in,
                              void* d_out, int out_size, void* d_ws, size_t ws_size,
                              hipStream_t stream) {
    (void)in_sizes; (void)n_in; (void)out_size; (void)ws_size;
    const float* x       = (const float*)d_in[0];
    const float* coords  = (const float*)d_in[1];
    const float* anchors = (const float*)d_in[2];
    const float* fcw     = (const float*)d_in[3];
    const float* fcb     = (const float*)d_in[4];
    const float* gamma   = (const float*)d_in[5];
    const float* beta    = (const float*)d_in[6];
    float* out = (float*)d_out;

    char* ws = (char*)d_ws;
    int*   ws_idx   = (int*)  (ws + 0);          // 6,291,456 B
    int*   ws_deg   = (int*)  (ws + 6291456);    //     8,192 B
    int*   ws_offs  = (int*)  (ws + 6299648);    //     8,192 B
    int*   ws_cur   = (int*)  (ws + 6307840);    //     8,192 B
    int*   ws_list  = (int*)  (ws + 6316032);    // 6,291,456 B
    float* ws_ep    = (float*)(ws + 12607488);   // 2,097,152 B
    float* ws_wt    = (float*)(ws + 14704640);   //   262,144 B
    float* ws_bn1   = (float*)(ws + 14966784);   // 2,097,152 B
    float* ws_bn2   = (float*)(ws + 17063936);   // 2,097,152 B
    float* ws_ab    = (float*)(ws + 19161088);   //     2,048 B

    hipMemsetAsync(ws_deg, 0, BB * MM * sizeof(int), stream);
    hipMemsetAsync(ws_cur, 0, BB * MM * sizeof(int), stream);

    hipLaunchKernelGGL(k_wt,      dim3(256),   dim3(256), 0, stream, fcw, ws_wt);
    hipLaunchKernelGGL(k_topk,    dim3(512),   dim3(128), 0, stream, coords, anchors, ws_idx, ws_deg);
    hipLaunchKernelGGL(k_offsets, dim3(1),     dim3(256), 0, stream, ws_deg, ws_offs);
    hipLaunchKernelGGL(k_fill,    dim3(256),   dim3(256), 0, stream, ws_idx, ws_offs, ws_cur, ws_list);
    hipLaunchKernelGGL(k_edge2,   dim3(2048),  dim3(256), 0, stream, x, ws_list, ws_offs, ws_deg, ws_wt, fcb, ws_ep);
    hipLaunchKernelGGL(k_gather,  dim3(2048),  dim3(256), 0, stream, x, ws_idx, ws_ep, out, ws_bn1, ws_bn2);
    hipLaunchKernelGGL(k_stats,   dim3(256),   dim3(256), 0, stream, ws_bn1, ws_bn2, gamma, beta, ws_ab);
    hipLaunchKernelGGL(k_silu,    dim3(16384), dim3(256), 0, stream, out, ws_ab);
}

// Round 3
// 763.337 us; speedup vs baseline: 3.6875x; 1.4598x over previous
//
#include <hip/hip_runtime.h>

#define BB 4
#define NN 16384
#define MM 512
#define CCH 256
#define KNN 24
#define EPSV 1e-5f

// ---------------- K0: transpose fc_w (256x256) -> Wt[cin][cout] ----------------
__global__ __launch_bounds__(256) void k_wt(const float* __restrict__ W, float* __restrict__ Wt) {
    int i = blockIdx.x * 256 + threadIdx.x;   // 65536
    int co = i >> 8, ci = i & 255;
    Wt[(ci << 8) + co] = W[i];
}

// ---------------- K1: top-24 nearest anchors per node (register list) ----------------
// 512 blocks x 128 threads; block = (b, 128-node chunk). Top-24 kept in VGPRs via
// fully-unrolled compare-select chain (no LDS list, no divergent while).
__global__ __launch_bounds__(128) void k_topk(const float* __restrict__ coords,
                                              const float* __restrict__ anchors,
                                              int* __restrict__ idx_out,
                                              int* __restrict__ deg) {
    __shared__ float4 alds[MM];     // 8 KB: x,y,z,|a|^2
    __shared__ int    hist[MM];     // 2 KB
    int tid = threadIdx.x;
    int blk = blockIdx.x;           // 512 blocks: 128 per batch
    int b = blk >> 7;
    int n0 = (blk & 127) << 7;

    for (int m = tid; m < MM; m += 128) {
        float x_ = anchors[(b * MM + m) * 3 + 0];
        float y_ = anchors[(b * MM + m) * 3 + 1];
        float z_ = anchors[(b * MM + m) * 3 + 2];
        alds[m] = make_float4(x_, y_, z_, x_ * x_ + y_ * y_ + z_ * z_);
        hist[m] = 0;
    }
    __syncthreads();

    int n = n0 + tid;
    float cx = coords[(b * NN + n) * 3 + 0];
    float cy = coords[(b * NN + n) * 3 + 1];
    float cz = coords[(b * NN + n) * 3 + 2];
    float cn2 = cx * cx + cy * cy + cz * cz;

    float dst[KNN];
    int   ids[KNN];
    #pragma unroll
    for (int j = 0; j < KNN; ++j) { dst[j] = 3.4e38f; ids[j] = 0; }

    float4 a = alds[0];
    for (int m = 0; m < MM; ++m) {
        float4 nx = alds[(m + 1) & (MM - 1)];       // prefetch (wraps on last)
        float dot = cx * a.x + cy * a.y + cz * a.z;
        float cd = cn2 + a.w - 2.0f * dot;          // same arithmetic as reference
        int   ci = m;
        // bubble candidate down the ascending list; strict < keeps earlier index on tie
        #pragma unroll
        for (int j = 0; j < KNN; ++j) {
            bool c = cd < dst[j];
            float t  = dst[j];
            int   ti = ids[j];
            dst[j] = c ? cd : t;
            ids[j] = c ? ci : ti;
            cd = c ? t : cd;
            ci = c ? ti : ci;
        }
        a = nx;
    }

    // per-block LDS histogram of edge degrees
    #pragma unroll
    for (int j = 0; j < KNN; ++j) atomicAdd(&hist[ids[j]], 1);

    // write this node's 24 indices as 6 int4 stores (96B contiguous per thread)
    int4* op = (int4*)(idx_out + (size_t)(b * NN + n) * KNN);
    op[0] = make_int4(ids[0],  ids[1],  ids[2],  ids[3]);
    op[1] = make_int4(ids[4],  ids[5],  ids[6],  ids[7]);
    op[2] = make_int4(ids[8],  ids[9],  ids[10], ids[11]);
    op[3] = make_int4(ids[12], ids[13], ids[14], ids[15]);
    op[4] = make_int4(ids[16], ids[17], ids[18], ids[19]);
    op[5] = make_int4(ids[20], ids[21], ids[22], ids[23]);

    __syncthreads();
    for (int m = tid; m < MM; m += 128) {
        int h = hist[m];
        if (h) atomicAdd(&deg[(b << 9) + m], h);
    }
}

// ---------------- K2a: exclusive prefix sum of deg (2048) -> offs ----------------
__global__ __launch_bounds__(256) void k_offsets(const int* __restrict__ deg,
                                                 int* __restrict__ offs) {
    __shared__ int part[256];
    int t = threadIdx.x;
    int v[8];
    int s = 0;
    #pragma unroll
    for (int j = 0; j < 8; ++j) { v[j] = deg[t * 8 + j]; s += v[j]; }
    part[t] = s;
    __syncthreads();
    for (int off = 1; off < 256; off <<= 1) {
        int val = (t >= off) ? part[t - off] : 0;
        __syncthreads();
        part[t] += val;
        __syncthreads();
    }
    int excl = part[t] - s;
    #pragma unroll
    for (int j = 0; j < 8; ++j) { offs[t * 8 + j] = excl; excl += v[j]; }
}

// ---------------- K2b: fill CSR member lists (node ids per edge) ----------------
__global__ __launch_bounds__(256) void k_fill(const int* __restrict__ idxb,
                                              const int* __restrict__ offs,
                                              int* __restrict__ cur,
                                              int* __restrict__ list) {
    int gn = blockIdx.x * 256 + threadIdx.x;   // 0..65535
    int b = gn >> 14;
    #pragma unroll
    for (int k = 0; k < KNN; ++k) {
        int m = idxb[gn * KNN + k];
        int e = (b << 9) + m;
        int p = atomicAdd(&cur[e], 1);
        list[offs[e] + p] = gn & 16383;
    }
}

// ---------------- K3: E' = ((gather(x)*inv_e)@W^T + b*(deg>0)) / 24 ----------------
__global__ __launch_bounds__(256) void k_edge2(const float* __restrict__ x,
                                               const int* __restrict__ list,
                                               const int* __restrict__ offs,
                                               const int* __restrict__ deg,
                                               const float* __restrict__ Wt,
                                               const float* __restrict__ fcb,
                                               float* __restrict__ Ep) {
    __shared__ int nl[256];
    __shared__ float srow[CCH];
    int tid = threadIdx.x;
    int blk = blockIdx.x;     // b*512 + m
    int b = blk >> 9;
    int d = deg[blk];
    int o = offs[blk];
    const float* xb = x + ((size_t)b << 22);   // b * NN * CCH

    float a0 = 0.f, a1 = 0.f, a2 = 0.f, a3 = 0.f;
    for (int base = 0; base < d; base += 256) {
        int cnt = min(256, d - base);
        if (tid < cnt) nl[tid] = list[o + base + tid];
        __syncthreads();
        int i = 0;
        for (; i + 3 < cnt; i += 4) {
            const float* p0 = xb + (nl[i + 0] << 8);
            const float* p1 = xb + (nl[i + 1] << 8);
            const float* p2 = xb + (nl[i + 2] << 8);
            const float* p3 = xb + (nl[i + 3] << 8);
            a0 += p0[tid]; a1 += p1[tid]; a2 += p2[tid]; a3 += p3[tid];
        }
        for (; i < cnt; ++i) a0 += xb[(nl[i] << 8) + tid];
        __syncthreads();
    }
    float inv = (d > 0) ? (1.0f / (float)d) : 0.0f;
    srow[tid] = ((a0 + a1) + (a2 + a3)) * inv;
    __syncthreads();

    float c0 = (d > 0) ? fcb[tid] : 0.0f;
    float c1 = 0.f, c2 = 0.f, c3 = 0.f;
    #pragma unroll 4
    for (int ci = 0; ci < CCH; ci += 4) {
        c0 = fmaf(srow[ci + 0], Wt[((ci + 0) << 8) + tid], c0);
        c1 = fmaf(srow[ci + 1], Wt[((ci + 1) << 8) + tid], c1);
        c2 = fmaf(srow[ci + 2], Wt[((ci + 2) << 8) + tid], c2);
        c3 = fmaf(srow[ci + 3], Wt[((ci + 3) << 8) + tid], c3);
    }
    Ep[(blk << 8) + tid] = ((c0 + c1) + (c2 + c3)) * (1.0f / 24.0f);
}

// ---------------- K4: out = H@E' + x, transposed write + BN partials ----------------
#define NODES4 32
__global__ __launch_bounds__(256) void k_gather(const float* __restrict__ x,
                                                const int* __restrict__ idxb,
                                                const float* __restrict__ Ep,
                                                float* __restrict__ out,
                                                float* __restrict__ bn1,
                                                float* __restrict__ bn2) {
    __shared__ int   it[NODES4 * KNN];          // 768 ints
    __shared__ float tile[CCH][NODES4 + 1];     // 33.8 KB
    int tid = threadIdx.x;
    int blk = blockIdx.x;                       // 2048: b * 512 node-chunks
    int b = blk >> 9;
    int n0 = (blk & 511) * NODES4;

    for (int i = tid; i < NODES4 * KNN; i += 256)
        it[i] = idxb[(b * NN + n0) * KNN + i];
    __syncthreads();

    const float* Eb = Ep + ((b * MM) << 8);
    float sum = 0.0f, ss = 0.0f;
    for (int j = 0; j < NODES4; ++j) {
        int n = n0 + j;
        float a0 = 0.f, a1 = 0.f, a2 = 0.f, a3 = 0.f;
        #pragma unroll
        for (int k = 0; k < KNN; k += 4) {
            a0 += Eb[(it[j * KNN + k + 0] << 8) + tid];
            a1 += Eb[(it[j * KNN + k + 1] << 8) + tid];
            a2 += Eb[(it[j * KNN + k + 2] << 8) + tid];
            a3 += Eb[(it[j * KNN + k + 3] << 8) + tid];
        }
        float o = x[((b * NN + n) << 8) + tid] + ((a0 + a1) + (a2 + a3));
        tile[tid][j] = o;
        sum += o; ss += o * o;
    }
    bn1[blk * 256 + tid] = sum;                 // coalesced
    bn2[blk * 256 + tid] = ss;
    __syncthreads();
    // dump transposed: out[b][c][n0 + j]
    for (int i = tid; i < CCH * NODES4; i += 256) {
        int c2 = i >> 5;
        int j2 = i & 31;
        out[((b * CCH + c2) << 14) + n0 + j2] = tile[c2][j2];
    }
}

// ---------------- K5: finalize BN stats -> a[c], bb[c] ----------------
__global__ __launch_bounds__(256) void k_stats(const float* __restrict__ bn1,
                                               const float* __restrict__ bn2,
                                               const float* __restrict__ gamma,
                                               const float* __restrict__ beta,
                                               float* __restrict__ ab) {
    __shared__ float r1[256], r2[256];
    int c = blockIdx.x;
    int t = threadIdx.x;
    float s1 = 0.f, s2 = 0.f;
    for (int i = t; i < 2048; i += 256) {
        s1 += bn1[i * 256 + c];
        s2 += bn2[i * 256 + c];
    }
    r1[t] = s1; r2[t] = s2;
    __syncthreads();
    for (int o = 128; o > 0; o >>= 1) {
        if (t < o) { r1[t] += r1[t + o]; r2[t] += r2[t + o]; }
        __syncthreads();
    }
    if (t == 0) {
        float mean = r1[0] * (1.0f / 65536.0f);
        float var  = r2[0] * (1.0f / 65536.0f) - mean * mean;
        float istd = rsqrtf(var + EPSV);
        float a = gamma[c] * istd;
        ab[c] = a;
        ab[CCH + c] = beta[c] - mean * a;
    }
}

// ---------------- K6: in-place normalize + SiLU ----------------
__global__ __launch_bounds__(256) void k_silu(float* __restrict__ out,
                                              const float* __restrict__ ab) {
    int i = blockIdx.x * 256 + threadIdx.x;     // float4 index, 4194304 total
    int c = (i >> 12) & 255;                    // 4096 float4 per (b,c) row
    float a = ab[c], bb = ab[CCH + c];
    float4 v = ((float4*)out)[i];
    float t0 = a * v.x + bb;
    float t1 = a * v.y + bb;
    float t2 = a * v.z + bb;
    float t3 = a * v.w + bb;
    v.x = t0 / (1.0f + __expf(-t0));
    v.y = t1 / (1.0f + __expf(-t1));
    v.z = t2 / (1.0f + __expf(-t2));
    v.w = t3 / (1.0f + __expf(-t3));
    ((float4*)out)[i] = v;
}

extern "C" void kernel_launch(void* const* d_in, const int* in_sizes, int n_in,
                              void* d_out, int out_size, void* d_ws, size_t ws_size,
                              hipStream_t stream) {
    (void)in_sizes; (void)n_in; (void)out_size; (void)ws_size;
    const float* x       = (const float*)d_in[0];
    const float* coords  = (const float*)d_in[1];
    const float* anchors = (const float*)d_in[2];
    const float* fcw     = (const float*)d_in[3];
    const float* fcb     = (const float*)d_in[4];
    const float* gamma   = (const float*)d_in[5];
    const float* beta    = (const float*)d_in[6];
    float* out = (float*)d_out;

    char* ws = (char*)d_ws;
    int*   ws_idx   = (int*)  (ws + 0);          // 6,291,456 B
    int*   ws_deg   = (int*)  (ws + 6291456);    //     8,192 B
    int*   ws_offs  = (int*)  (ws + 6299648);    //     8,192 B
    int*   ws_cur   = (int*)  (ws + 6307840);    //     8,192 B
    int*   ws_list  = (int*)  (ws + 6316032);    // 6,291,456 B
    float* ws_ep    = (float*)(ws + 12607488);   // 2,097,152 B
    float* ws_wt    = (float*)(ws + 14704640);   //   262,144 B
    float* ws_bn1   = (float*)(ws + 14966784);   // 2,097,152 B
    float* ws_bn2   = (float*)(ws + 17063936);   // 2,097,152 B
    float* ws_ab    = (float*)(ws + 19161088);   //     2,048 B

    hipMemsetAsync(ws_deg, 0, BB * MM * sizeof(int), stream);
    hipMemsetAsync(ws_cur, 0, BB * MM * sizeof(int), stream);

    hipLaunchKernelGGL(k_wt,      dim3(256),   dim3(256), 0, stream, fcw, ws_wt);
    hipLaunchKernelGGL(k_topk,    dim3(512),   dim3(128), 0, stream, coords, anchors, ws_idx, ws_deg);
    hipLaunchKernelGGL(k_offsets, dim3(1),     dim3(256), 0, stream, ws_deg, ws_offs);
    hipLaunchKernelGGL(k_fill,    dim3(256),   dim3(256), 0, stream, ws_idx, ws_offs, ws_cur, ws_list);
    hipLaunchKernelGGL(k_edge2,   dim3(2048),  dim3(256), 0, stream, x, ws_list, ws_offs, ws_deg, ws_wt, fcb, ws_ep);
    hipLaunchKernelGGL(k_gather,  dim3(2048),  dim3(256), 0, stream, x, ws_idx, ws_ep, out, ws_bn1, ws_bn2);
    hipLaunchKernelGGL(k_stats,   dim3(256),   dim3(256), 0, stream, ws_bn1, ws_bn2, gamma, beta, ws_ab);
    hipLaunchKernelGGL(k_silu,    dim3(16384), dim3(256), 0, stream, out, ws_ab);
}

// Round 4
// 750.276 us; speedup vs baseline: 3.7517x; 1.0174x over previous
//
#include <hip/hip_runtime.h>

#define BB 4
#define NN 16384
#define MM 512
#define CCH 256
#define KNN 24
#define EPSV 1e-5f

// ---------------- K0: transpose fc_w (256x256) -> Wt[cin][cout] ----------------
__global__ __launch_bounds__(256) void k_wt(const float* __restrict__ W, float* __restrict__ Wt) {
    int i = blockIdx.x * 256 + threadIdx.x;   // 65536
    int co = i >> 8, ci = i & 255;
    Wt[(ci << 8) + co] = W[i];
}

// ---------------- K1: top-24 nearest anchors, 2 lanes/node ----------------
// 1024 blocks x 128 threads. Wave covers 32 nodes; lanes l / l+32 split the 512
// anchors 0-255 / 256-511, each keeps a register-resident sorted top-24, then the
// pair merges via min(a[i], b[23-i]) with __shfl_xor(32). launch_bounds(128,2)
// caps at 256 VGPR so the lists stay in VGPRs (round-3's 40-VGPR alloc pushed
// them to AGPRs: ~350 inst/anchor instead of ~135).
__global__ __launch_bounds__(128, 2) void k_topk(const float* __restrict__ coords,
                                                 const float* __restrict__ anchors,
                                                 int* __restrict__ idx_out,
                                                 int* __restrict__ deg) {
    __shared__ float4 alds[MM];     // 8 KB: x,y,z,|a|^2
    __shared__ int    hist[MM];     // 2 KB
    int tid = threadIdx.x;
    int blk = blockIdx.x;           // 1024 blocks: 256 per batch
    int b  = blk >> 8;
    int n0 = (blk & 255) << 6;      // 64 nodes per block
    int lane = tid & 63;
    int half = lane >> 5;           // 0: anchors 0..255, 1: 256..511
    int n = n0 + ((tid >> 6) << 5) + (lane & 31);

    for (int m = tid; m < MM; m += 128) {
        float x_ = anchors[(b * MM + m) * 3 + 0];
        float y_ = anchors[(b * MM + m) * 3 + 1];
        float z_ = anchors[(b * MM + m) * 3 + 2];
        alds[m] = make_float4(x_, y_, z_, x_ * x_ + y_ * y_ + z_ * z_);
        hist[m] = 0;
    }
    __syncthreads();

    float cx = coords[(b * NN + n) * 3 + 0];
    float cy = coords[(b * NN + n) * 3 + 1];
    float cz = coords[(b * NN + n) * 3 + 2];
    float cn2 = cx * cx + cy * cy + cz * cz;

    float d[KNN];
    int   id[KNN];
    #pragma unroll
    for (int j = 0; j < KNN; ++j) { d[j] = 3.4e38f; id[j] = 0; }

    int base = half << 8;
    float4 a = alds[base];
    for (int mm = 0; mm < 256; ++mm) {
        float4 nx = alds[base + ((mm + 1) & 255)];      // prefetch (wraps)
        float cd = cn2 + a.w - 2.0f * (cx * a.x + cy * a.y + cz * a.z);
        int   ci = base + mm;
        bool ins = false;                               // carry flag: keep shifting after insert
        #pragma unroll
        for (int j = 0; j < KNN; ++j) {
            bool c = ins | (cd < d[j]);
            float td = d[j]; int ti = id[j];
            d[j]  = c ? cd : td;
            id[j] = c ? ci : ti;
            cd = c ? td : cd;
            ci = c ? ti : ci;
            ins = c;
        }
        a = nx;
    }

    // pair-merge: global top-24 = { min(a[i], b[23-i]) }.  Lower lane produces
    // i=0..11, upper lane i=12..23 (only ids needed downstream; tie -> a).
    int Mi[12];
    #pragma unroll
    for (int j = 0; j < 12; ++j) {
        float sA = __shfl_xor(d[23 - j], 32);   // partner's d[23-j]
        int   iA = __shfl_xor(id[23 - j], 32);
        float sB = __shfl_xor(d[12 + j], 32);   // partner's d[12+j]
        int   iB = __shfl_xor(id[12 + j], 32);
        float av, bv; int ai_, bi_;
        if (half == 0) { av = d[j];      ai_ = id[j];      bv = sA;         bi_ = iA; }
        else           { av = sB;        ai_ = iB;         bv = d[11 - j];  bi_ = id[11 - j]; }
        bool c = av <= bv;
        Mi[j] = c ? ai_ : bi_;
    }

    #pragma unroll
    for (int j = 0; j < 12; ++j) atomicAdd(&hist[Mi[j]], 1);

    int* op = idx_out + (size_t)(b * NN + n) * KNN + half * 12;
    ((int4*)op)[0] = make_int4(Mi[0], Mi[1], Mi[2],  Mi[3]);
    ((int4*)op)[1] = make_int4(Mi[4], Mi[5], Mi[6],  Mi[7]);
    ((int4*)op)[2] = make_int4(Mi[8], Mi[9], Mi[10], Mi[11]);

    __syncthreads();
    for (int m = tid; m < MM; m += 128) {
        int h = hist[m];
        if (h) atomicAdd(&deg[(b << 9) + m], h);
    }
}

// ---------------- K2a: exclusive prefix sum of deg (2048) -> offs ----------------
__global__ __launch_bounds__(256) void k_offsets(const int* __restrict__ deg,
                                                 int* __restrict__ offs) {
    __shared__ int part[256];
    int t = threadIdx.x;
    int v[8];
    int s = 0;
    #pragma unroll
    for (int j = 0; j < 8; ++j) { v[j] = deg[t * 8 + j]; s += v[j]; }
    part[t] = s;
    __syncthreads();
    for (int off = 1; off < 256; off <<= 1) {
        int val = (t >= off) ? part[t - off] : 0;
        __syncthreads();
        part[t] += val;
        __syncthreads();
    }
    int excl = part[t] - s;
    #pragma unroll
    for (int j = 0; j < 8; ++j) { offs[t * 8 + j] = excl; excl += v[j]; }
}

// ---------------- K2b: fill CSR member lists (node ids per edge) ----------------
__global__ __launch_bounds__(256) void k_fill(const int* __restrict__ idxb,
                                              const int* __restrict__ offs,
                                              int* __restrict__ cur,
                                              int* __restrict__ list) {
    int gn = blockIdx.x * 256 + threadIdx.x;   // 0..65535
    int b = gn >> 14;
    #pragma unroll
    for (int k = 0; k < KNN; ++k) {
        int m = idxb[gn * KNN + k];
        int e = (b << 9) + m;
        int p = atomicAdd(&cur[e], 1);
        list[offs[e] + p] = gn & 16383;
    }
}

// ---------------- K3: E' = ((gather(x)*inv_e)@W^T + b*(deg>0)) / 24 ----------------
__global__ __launch_bounds__(256) void k_edge2(const float* __restrict__ x,
                                               const int* __restrict__ list,
                                               const int* __restrict__ offs,
                                               const int* __restrict__ deg,
                                               const float* __restrict__ Wt,
                                               const float* __restrict__ fcb,
                                               float* __restrict__ Ep) {
    __shared__ int nl[256];
    __shared__ float srow[CCH];
    int tid = threadIdx.x;
    int blk = blockIdx.x;     // b*512 + m
    int b = blk >> 9;
    int d = deg[blk];
    int o = offs[blk];
    const float* xb = x + ((size_t)b << 22);   // b * NN * CCH

    float a0 = 0.f, a1 = 0.f, a2 = 0.f, a3 = 0.f;
    for (int base = 0; base < d; base += 256) {
        int cnt = min(256, d - base);
        if (tid < cnt) nl[tid] = list[o + base + tid];
        __syncthreads();
        int i = 0;
        for (; i + 3 < cnt; i += 4) {
            const float* p0 = xb + (nl[i + 0] << 8);
            const float* p1 = xb + (nl[i + 1] << 8);
            const float* p2 = xb + (nl[i + 2] << 8);
            const float* p3 = xb + (nl[i + 3] << 8);
            a0 += p0[tid]; a1 += p1[tid]; a2 += p2[tid]; a3 += p3[tid];
        }
        for (; i < cnt; ++i) a0 += xb[(nl[i] << 8) + tid];
        __syncthreads();
    }
    float inv = (d > 0) ? (1.0f / (float)d) : 0.0f;
    srow[tid] = ((a0 + a1) + (a2 + a3)) * inv;
    __syncthreads();

    float c0 = (d > 0) ? fcb[tid] : 0.0f;
    float c1 = 0.f, c2 = 0.f, c3 = 0.f;
    #pragma unroll 4
    for (int ci = 0; ci < CCH; ci += 4) {
        c0 = fmaf(srow[ci + 0], Wt[((ci + 0) << 8) + tid], c0);
        c1 = fmaf(srow[ci + 1], Wt[((ci + 1) << 8) + tid], c1);
        c2 = fmaf(srow[ci + 2], Wt[((ci + 2) << 8) + tid], c2);
        c3 = fmaf(srow[ci + 3], Wt[((ci + 3) << 8) + tid], c3);
    }
    Ep[(blk << 8) + tid] = ((c0 + c1) + (c2 + c3)) * (1.0f / 24.0f);
}

// ---------------- K4: out = H@E' + x, transposed write + BN partials ----------------
#define NODES4 32
__global__ __launch_bounds__(256) void k_gather(const float* __restrict__ x,
                                                const int* __restrict__ idxb,
                                                const float* __restrict__ Ep,
                                                float* __restrict__ out,
                                                float* __restrict__ bn1,
                                                float* __restrict__ bn2) {
    __shared__ int   it[NODES4 * KNN];          // 768 ints
    __shared__ float tile[CCH][NODES4 + 1];     // 33.8 KB
    int tid = threadIdx.x;
    int blk = blockIdx.x;                       // 2048: b * 512 node-chunks
    int b = blk >> 9;
    int n0 = (blk & 511) * NODES4;

    for (int i = tid; i < NODES4 * KNN; i += 256)
        it[i] = idxb[(b * NN + n0) * KNN + i];
    __syncthreads();

    const float* Eb = Ep + ((b * MM) << 8);
    float sum = 0.0f, ss = 0.0f;
    for (int j = 0; j < NODES4; ++j) {
        int n = n0 + j;
        float a0 = 0.f, a1 = 0.f, a2 = 0.f, a3 = 0.f;
        #pragma unroll
        for (int k = 0; k < KNN; k += 4) {
            a0 += Eb[(it[j * KNN + k + 0] << 8) + tid];
            a1 += Eb[(it[j * KNN + k + 1] << 8) + tid];
            a2 += Eb[(it[j * KNN + k + 2] << 8) + tid];
            a3 += Eb[(it[j * KNN + k + 3] << 8) + tid];
        }
        float o = x[((b * NN + n) << 8) + tid] + ((a0 + a1) + (a2 + a3));
        tile[tid][j] = o;
        sum += o; ss += o * o;
    }
    bn1[blk * 256 + tid] = sum;                 // coalesced
    bn2[blk * 256 + tid] = ss;
    __syncthreads();
    // dump transposed: out[b][c][n0 + j]
    for (int i = tid; i < CCH * NODES4; i += 256) {
        int c2 = i >> 5;
        int j2 = i & 31;
        out[((b * CCH + c2) << 14) + n0 + j2] = tile[c2][j2];
    }
}

// ---------------- K5: finalize BN stats -> a[c], bb[c] ----------------
__global__ __launch_bounds__(256) void k_stats(const float* __restrict__ bn1,
                                               const float* __restrict__ bn2,
                                               const float* __restrict__ gamma,
                                               const float* __restrict__ beta,
                                               float* __restrict__ ab) {
    __shared__ float r1[256], r2[256];
    int c = blockIdx.x;
    int t = threadIdx.x;
    float s1 = 0.f, s2 = 0.f;
    for (int i = t; i < 2048; i += 256) {
        s1 += bn1[i * 256 + c];
        s2 += bn2[i * 256 + c];
    }
    r1[t] = s1; r2[t] = s2;
    __syncthreads();
    for (int o = 128; o > 0; o >>= 1) {
        if (t < o) { r1[t] += r1[t + o]; r2[t] += r2[t + o]; }
        __syncthreads();
    }
    if (t == 0) {
        float mean = r1[0] * (1.0f / 65536.0f);
        float var  = r2[0] * (1.0f / 65536.0f) - mean * mean;
        float istd = rsqrtf(var + EPSV);
        float a = gamma[c] * istd;
        ab[c] = a;
        ab[CCH + c] = beta[c] - mean * a;
    }
}

// ---------------- K6: in-place normalize + SiLU ----------------
__global__ __launch_bounds__(256) void k_silu(float* __restrict__ out,
                                              const float* __restrict__ ab) {
    int i = blockIdx.x * 256 + threadIdx.x;     // float4 index, 4194304 total
    int c = (i >> 12) & 255;                    // 4096 float4 per (b,c) row
    float a = ab[c], bb = ab[CCH + c];
    float4 v = ((float4*)out)[i];
    float t0 = a * v.x + bb;
    float t1 = a * v.y + bb;
    float t2 = a * v.z + bb;
    float t3 = a * v.w + bb;
    v.x = t0 / (1.0f + __expf(-t0));
    v.y = t1 / (1.0f + __expf(-t1));
    v.z = t2 / (1.0f + __expf(-t2));
    v.w = t3 / (1.0f + __expf(-t3));
    ((float4*)out)[i] = v;
}

extern "C" void kernel_launch(void* const* d_in, const int* in_sizes, int n_in,
                              void* d_out, int out_size, void* d_ws, size_t ws_size,
                              hipStream_t stream) {
    (void)in_sizes; (void)n_in; (void)out_size; (void)ws_size;
    const float* x       = (const float*)d_in[0];
    const float* coords  = (const float*)d_in[1];
    const float* anchors = (const float*)d_in[2];
    const float* fcw     = (const float*)d_in[3];
    const float* fcb     = (const float*)d_in[4];
    const float* gamma   = (const float*)d_in[5];
    const float* beta    = (const float*)d_in[6];
    float* out = (float*)d_out;

    char* ws = (char*)d_ws;
    int*   ws_idx   = (int*)  (ws + 0);          // 6,291,456 B
    int*   ws_deg   = (int*)  (ws + 6291456);    //     8,192 B
    int*   ws_offs  = (int*)  (ws + 6299648);    //     8,192 B
    int*   ws_cur   = (int*)  (ws + 6307840);    //     8,192 B
    int*   ws_list  = (int*)  (ws + 6316032);    // 6,291,456 B
    float* ws_ep    = (float*)(ws + 12607488);   // 2,097,152 B
    float* ws_wt    = (float*)(ws + 14704640);   //   262,144 B
    float* ws_bn1   = (float*)(ws + 14966784);   // 2,097,152 B
    float* ws_bn2   = (float*)(ws + 17063936);   // 2,097,152 B
    float* ws_ab    = (float*)(ws + 19161088);   //     2,048 B

    hipMemsetAsync(ws_deg, 0, BB * MM * sizeof(int), stream);
    hipMemsetAsync(ws_cur, 0, BB * MM * sizeof(int), stream);

    hipLaunchKernelGGL(k_wt,      dim3(256),   dim3(256), 0, stream, fcw, ws_wt);
    hipLaunchKernelGGL(k_topk,    dim3(1024),  dim3(128), 0, stream, coords, anchors, ws_idx, ws_deg);
    hipLaunchKernelGGL(k_offsets, dim3(1),     dim3(256), 0, stream, ws_deg, ws_offs);
    hipLaunchKernelGGL(k_fill,    dim3(256),   dim3(256), 0, stream, ws_idx, ws_offs, ws_cur, ws_list);
    hipLaunchKernelGGL(k_edge2,   dim3(2048),  dim3(256), 0, stream, x, ws_list, ws_offs, ws_deg, ws_wt, fcb, ws_ep);
    hipLaunchKernelGGL(k_gather,  dim3(2048),  dim3(256), 0, stream, x, ws_idx, ws_ep, out, ws_bn1, ws_bn2);
    hipLaunchKernelGGL(k_stats,   dim3(256),   dim3(256), 0, stream, ws_bn1, ws_bn2, gamma, beta, ws_ab);
    hipLaunchKernelGGL(k_silu,    dim3(16384), dim3(256), 0, stream, out, ws_ab);
}

// Round 6
// 620.375 us; speedup vs baseline: 4.5372x; 1.2094x over previous
//
#include <hip/hip_runtime.h>

#define BB 4
#define NN 16384
#define MM 512
#define CCH 256
#define KNN 24
#define EPSV 1e-5f

typedef unsigned short ushort_t;

__device__ __forceinline__ unsigned int pk_bf16(float a, float b) {
    unsigned int ua = __float_as_uint(a), ub = __float_as_uint(b);
    ua += 0x7FFFu + ((ua >> 16) & 1u);          // RNE to bf16
    ub += 0x7FFFu + ((ub >> 16) & 1u);
    return (ua >> 16) | (ub & 0xFFFF0000u);
}
__device__ __forceinline__ float lo_bf(unsigned int u) { return __uint_as_float(u << 16); }
__device__ __forceinline__ float hi_bf(unsigned int u) { return __uint_as_float(u & 0xFFFF0000u); }

// ---------------- K-1: pack x -> bf16 pairs (uint = 2 channels), lives in d_out ----------------
__global__ __launch_bounds__(256) void k_cvt(const float* __restrict__ x,
                                             unsigned int* __restrict__ xh) {
    int i = blockIdx.x * 256 + threadIdx.x;   // 8,388,608 float2s
    float2 v = ((const float2*)x)[i];
    xh[i] = pk_bf16(v.x, v.y);
}

// ---------------- K0: transpose fc_w (256x256) -> Wt[cin][cout] ----------------
__global__ __launch_bounds__(256) void k_wt(const float* __restrict__ W, float* __restrict__ Wt) {
    int i = blockIdx.x * 256 + threadIdx.x;   // 65536
    int co = i >> 8, ci = i & 255;
    Wt[(ci << 8) + co] = W[i];
}

// ---------------- K1: top-24 nearest anchors, 2 lanes/node (round-4 proven) ----------------
// 1024 blocks x 128 threads. Lanes l / l+32 split the 512 anchors 0-255 / 256-511,
// each keeps a register-resident sorted top-24 (launch_bounds(128,2) -> stays in
// VGPRs), then the pair merges via min(a[i], b[23-i]) with __shfl_xor(32).
// Only change vs the proven round-4 kernel: indices stored packed-ushort.
__global__ __launch_bounds__(128, 2) void k_topk(const float* __restrict__ coords,
                                                 const float* __restrict__ anchors,
                                                 ushort_t* __restrict__ idx_out,
                                                 int* __restrict__ deg) {
    __shared__ float4 alds[MM];     // 8 KB: x,y,z,|a|^2
    __shared__ int    hist[MM];     // 2 KB
    int tid = threadIdx.x;
    int blk = blockIdx.x;           // 1024 blocks: 256 per batch
    int b  = blk >> 8;
    int n0 = (blk & 255) << 6;      // 64 nodes per block
    int lane = tid & 63;
    int half = lane >> 5;           // 0: anchors 0..255, 1: 256..511
    int n = n0 + ((tid >> 6) << 5) + (lane & 31);

    for (int m = tid; m < MM; m += 128) {
        float x_ = anchors[(b * MM + m) * 3 + 0];
        float y_ = anchors[(b * MM + m) * 3 + 1];
        float z_ = anchors[(b * MM + m) * 3 + 2];
        alds[m] = make_float4(x_, y_, z_, x_ * x_ + y_ * y_ + z_ * z_);
        hist[m] = 0;
    }
    __syncthreads();

    float cx = coords[(b * NN + n) * 3 + 0];
    float cy = coords[(b * NN + n) * 3 + 1];
    float cz = coords[(b * NN + n) * 3 + 2];
    float cn2 = cx * cx + cy * cy + cz * cz;

    float d[KNN];
    int   id[KNN];
    #pragma unroll
    for (int j = 0; j < KNN; ++j) { d[j] = 3.4e38f; id[j] = 0; }

    int base = half << 8;
    float4 a = alds[base];
    for (int mm = 0; mm < 256; ++mm) {
        float4 nx = alds[base + ((mm + 1) & 255)];      // prefetch (wraps)
        float cd = cn2 + a.w - 2.0f * (cx * a.x + cy * a.y + cz * a.z);
        int   ci = base + mm;
        bool ins = false;                               // carry flag: keep shifting after insert
        #pragma unroll
        for (int j = 0; j < KNN; ++j) {
            bool c = ins | (cd < d[j]);
            float td = d[j]; int ti = id[j];
            d[j]  = c ? cd : td;
            id[j] = c ? ci : ti;
            cd = c ? td : cd;
            ci = c ? ti : ci;
            ins = c;
        }
        a = nx;
    }

    // pair-merge: global top-24 = { min(a[i], b[23-i]) }.  Lower lane produces
    // i=0..11, upper lane i=12..23 (only ids needed downstream; tie -> a).
    int Mi[12];
    #pragma unroll
    for (int j = 0; j < 12; ++j) {
        float sA = __shfl_xor(d[23 - j], 32);   // partner's d[23-j]
        int   iA = __shfl_xor(id[23 - j], 32);
        float sB = __shfl_xor(d[12 + j], 32);   // partner's d[12+j]
        int   iB = __shfl_xor(id[12 + j], 32);
        float av, bv; int ai_, bi_;
        if (half == 0) { av = d[j];      ai_ = id[j];      bv = sA;         bi_ = iA; }
        else           { av = sB;        ai_ = iB;         bv = d[11 - j];  bi_ = id[11 - j]; }
        Mi[j] = (av <= bv) ? ai_ : bi_;
    }

    #pragma unroll
    for (int j = 0; j < 12; ++j) atomicAdd(&hist[Mi[j]], 1);

    // idx as ushort: node stride 24 ushorts (48B); half offset 12 (24B -> 4B aligned)
    unsigned int* ob = (unsigned int*)(idx_out + (size_t)(b * NN + n) * KNN + half * 12);
    ob[0] = (unsigned)(Mi[0] | (Mi[1] << 16));
    ob[1] = (unsigned)(Mi[2] | (Mi[3] << 16));
    ob[2] = (unsigned)(Mi[4] | (Mi[5] << 16));
    ob[3] = (unsigned)(Mi[6] | (Mi[7] << 16));
    ob[4] = (unsigned)(Mi[8] | (Mi[9] << 16));
    ob[5] = (unsigned)(Mi[10] | (Mi[11] << 16));

    __syncthreads();
    for (int m = tid; m < MM; m += 128) {
        int h = hist[m];
        if (h) atomicAdd(&deg[(b << 9) + m], h);
    }
}

// ---------------- K2a: exclusive prefix sum of deg (2048) -> offs ----------------
__global__ __launch_bounds__(256) void k_offsets(const int* __restrict__ deg,
                                                 int* __restrict__ offs) {
    __shared__ int part[256];
    int t = threadIdx.x;
    int v[8];
    int s = 0;
    #pragma unroll
    for (int j = 0; j < 8; ++j) { v[j] = deg[t * 8 + j]; s += v[j]; }
    part[t] = s;
    __syncthreads();
    for (int off = 1; off < 256; off <<= 1) {
        int val = (t >= off) ? part[t - off] : 0;
        __syncthreads();
        part[t] += val;
        __syncthreads();
    }
    int excl = part[t] - s;
    #pragma unroll
    for (int j = 0; j < 8; ++j) { offs[t * 8 + j] = excl; excl += v[j]; }
}

// ---------------- K2b: fill CSR member lists (node ids per edge, ushort) ----------------
__global__ __launch_bounds__(256) void k_fill(const ushort_t* __restrict__ idxb,
                                              const int* __restrict__ offs,
                                              int* __restrict__ cur,
                                              ushort_t* __restrict__ list) {
    int gn = blockIdx.x * 256 + threadIdx.x;   // 0..65535
    int b = gn >> 14;
    #pragma unroll
    for (int k = 0; k < KNN; ++k) {
        int m = idxb[(size_t)gn * KNN + k];
        int e = (b << 9) + m;
        int p = atomicAdd(&cur[e], 1);
        list[(size_t)offs[e] + p] = (ushort_t)(gn & 16383);
    }
}

// ---------------- K3: E' = ((gather(xh)*inv_e)@W^T + b*(deg>0)) / 24, bf16 out ----------------
__global__ __launch_bounds__(256) void k_edge2(const unsigned int* __restrict__ xh,
                                               const ushort_t* __restrict__ list,
                                               const int* __restrict__ offs,
                                               const int* __restrict__ deg,
                                               const float* __restrict__ Wt,
                                               const float* __restrict__ fcb,
                                               unsigned int* __restrict__ Eph) {
    __shared__ ushort_t nl[256];
    __shared__ float part[2][128][2];
    __shared__ float srow[CCH];
    __shared__ float rrow[CCH];
    int tid = threadIdx.x;
    int blk = blockIdx.x;               // b*512 + m
    int b = blk >> 9;
    int d = deg[blk];
    int o = offs[blk];
    int cp = tid & 127, rs = tid >> 7;  // channel pair, row parity
    const unsigned int* xb = xh + ((size_t)b << 21);   // b * NN * 128

    float l0 = 0.f, l1 = 0.f, l2 = 0.f, l3 = 0.f;
    float h0 = 0.f, h1 = 0.f, h2 = 0.f, h3 = 0.f;
    for (int base2 = 0; base2 < d; base2 += 256) {
        int cnt = min(256, d - base2);
        if (tid < cnt) nl[tid] = list[(size_t)o + base2 + tid];
        __syncthreads();
        int i = 0;
        for (; i + 7 < cnt; i += 8) {
            unsigned int u0 = xb[((size_t)nl[i + 0 + rs] << 7) + cp];
            unsigned int u1 = xb[((size_t)nl[i + 2 + rs] << 7) + cp];
            unsigned int u2 = xb[((size_t)nl[i + 4 + rs] << 7) + cp];
            unsigned int u3 = xb[((size_t)nl[i + 6 + rs] << 7) + cp];
            l0 += lo_bf(u0); h0 += hi_bf(u0);
            l1 += lo_bf(u1); h1 += hi_bf(u1);
            l2 += lo_bf(u2); h2 += hi_bf(u2);
            l3 += lo_bf(u3); h3 += hi_bf(u3);
        }
        for (; i + 1 < cnt; i += 2) {
            unsigned int u = xb[((size_t)nl[i + rs] << 7) + cp];
            l0 += lo_bf(u); h0 += hi_bf(u);
        }
        if (i < cnt && rs == 0) {
            unsigned int u = xb[((size_t)nl[i] << 7) + cp];
            l0 += lo_bf(u); h0 += hi_bf(u);
        }
        __syncthreads();
    }
    part[rs][cp][0] = (l0 + l1) + (l2 + l3);
    part[rs][cp][1] = (h0 + h1) + (h2 + h3);
    __syncthreads();
    float inv = (d > 0) ? (1.0f / (float)d) : 0.0f;
    srow[tid] = (part[0][tid >> 1][tid & 1] + part[1][tid >> 1][tid & 1]) * inv;
    __syncthreads();

    float c0 = (d > 0) ? fcb[tid] : 0.0f;
    float c1 = 0.f, c2 = 0.f, c3 = 0.f;
    #pragma unroll 4
    for (int ci = 0; ci < CCH; ci += 4) {
        c0 = fmaf(srow[ci + 0], Wt[((ci + 0) << 8) + tid], c0);
        c1 = fmaf(srow[ci + 1], Wt[((ci + 1) << 8) + tid], c1);
        c2 = fmaf(srow[ci + 2], Wt[((ci + 2) << 8) + tid], c2);
        c3 = fmaf(srow[ci + 3], Wt[((ci + 3) << 8) + tid], c3);
    }
    rrow[tid] = ((c0 + c1) + (c2 + c3)) * (1.0f / 24.0f);
    __syncthreads();
    if (tid < 128) Eph[(size_t)blk * 128 + tid] = pk_bf16(rrow[2 * tid], rrow[2 * tid + 1]);
}

// ---------------- K4: out = H@E' + x, transposed write + BN partials ----------------
__global__ __launch_bounds__(256) void k_gather(const float* __restrict__ x,
                                                const unsigned int* __restrict__ idxu,
                                                const unsigned int* __restrict__ Eph,
                                                float* __restrict__ out,
                                                float* __restrict__ bn1,
                                                float* __restrict__ bn2) {
    __shared__ int   it[32 * KNN];          // 768 ints
    __shared__ float tile[32][CCH + 1];     // 32 x 257 = 32.9 KB
    int tid = threadIdx.x;
    int blk = blockIdx.x;                   // 2048: b * 512 node-chunks
    int b = blk >> 9;
    int n0 = (blk & 511) << 5;              // 32 nodes
    int cp = tid & 127, rs = tid >> 7;

    for (int i = tid; i < 32 * 12; i += 256) {           // 384 packed uints
        unsigned int u = idxu[(size_t)(b * NN + n0) * 12 + i];
        it[2 * i] = u & 0xFFFF;
        it[2 * i + 1] = u >> 16;
    }
    __syncthreads();

    const unsigned int* Eb = Eph + ((size_t)(b * MM) << 7);
    for (int j2 = 0; j2 < 16; ++j2) {
        int j = 2 * j2 + rs;
        int n = n0 + j;
        const int* itj = &it[j * KNN];
        float al = 0.f, ah = 0.f, bl = 0.f, bh = 0.f;
        float cl = 0.f, ch = 0.f, dl = 0.f, dh = 0.f;
        #pragma unroll
        for (int k = 0; k < KNN; k += 4) {
            unsigned int u0 = Eb[((size_t)itj[k + 0] << 7) + cp];
            unsigned int u1 = Eb[((size_t)itj[k + 1] << 7) + cp];
            unsigned int u2 = Eb[((size_t)itj[k + 2] << 7) + cp];
            unsigned int u3 = Eb[((size_t)itj[k + 3] << 7) + cp];
            al += lo_bf(u0); ah += hi_bf(u0);
            bl += lo_bf(u1); bh += hi_bf(u1);
            cl += lo_bf(u2); ch += hi_bf(u2);
            dl += lo_bf(u3); dh += hi_bf(u3);
        }
        float2 xv = ((const float2*)(x + (((size_t)(b * NN + n)) << 8)))[cp];
        tile[j][2 * cp + 0] = xv.x + ((al + bl) + (cl + dl));
        tile[j][2 * cp + 1] = xv.y + ((ah + bh) + (ch + dh));
    }
    __syncthreads();

    float sum = 0.f, ss = 0.f;
    #pragma unroll 4
    for (int j = 0; j < 32; ++j) {
        float v = tile[j][tid];
        sum += v; ss += v * v;
    }
    bn1[(size_t)blk * 256 + tid] = sum;
    bn2[(size_t)blk * 256 + tid] = ss;

    for (int i = tid; i < CCH * 32; i += 256) {
        int c2 = i >> 5, j2 = i & 31;
        out[(((size_t)(b * CCH + c2)) << 14) + n0 + j2] = tile[j2][c2];
    }
}

// ---------------- K5: finalize BN stats -> a[c], bb[c] ----------------
__global__ __launch_bounds__(256) void k_stats(const float* __restrict__ bn1,
                                               const float* __restrict__ bn2,
                                               const float* __restrict__ gamma,
                                               const float* __restrict__ beta,
                                               float* __restrict__ ab) {
    __shared__ float r1[256], r2[256];
    int c = blockIdx.x;
    int t = threadIdx.x;
    float s1 = 0.f, s2 = 0.f;
    for (int i = t; i < 2048; i += 256) {
        s1 += bn1[i * 256 + c];
        s2 += bn2[i * 256 + c];
    }
    r1[t] = s1; r2[t] = s2;
    __syncthreads();
    for (int o = 128; o > 0; o >>= 1) {
        if (t < o) { r1[t] += r1[t + o]; r2[t] += r2[t + o]; }
        __syncthreads();
    }
    if (t == 0) {
        float mean = r1[0] * (1.0f / 65536.0f);
        float var  = r2[0] * (1.0f / 65536.0f) - mean * mean;
        float istd = rsqrtf(var + EPSV);
        float a = gamma[c] * istd;
        ab[c] = a;
        ab[CCH + c] = beta[c] - mean * a;
    }
}

// ---------------- K6: in-place normalize + SiLU ----------------
__global__ __launch_bounds__(256) void k_silu(float* __restrict__ out,
                                              const float* __restrict__ ab) {
    int i = blockIdx.x * 256 + threadIdx.x;     // float4 index, 4194304 total
    int c = (i >> 12) & 255;
    float a = ab[c], bb = ab[CCH + c];
    float4 v = ((float4*)out)[i];
    float t0 = a * v.x + bb;
    float t1 = a * v.y + bb;
    float t2 = a * v.z + bb;
    float t3 = a * v.w + bb;
    v.x = t0 / (1.0f + __expf(-t0));
    v.y = t1 / (1.0f + __expf(-t1));
    v.z = t2 / (1.0f + __expf(-t2));
    v.w = t3 / (1.0f + __expf(-t3));
    ((float4*)out)[i] = v;
}

extern "C" void kernel_launch(void* const* d_in, const int* in_sizes, int n_in,
                              void* d_out, int out_size, void* d_ws, size_t ws_size,
                              hipStream_t stream) {
    (void)in_sizes; (void)n_in; (void)out_size; (void)ws_size;
    const float* x       = (const float*)d_in[0];
    const float* coords  = (const float*)d_in[1];
    const float* anchors = (const float*)d_in[2];
    const float* fcw     = (const float*)d_in[3];
    const float* fcb     = (const float*)d_in[4];
    const float* gamma   = (const float*)d_in[5];
    const float* beta    = (const float*)d_in[6];
    float* out = (float*)d_out;

    // bf16-packed x lives in d_out (33.5 MB of 67 MB); dead before k_gather
    // overwrites d_out. Keeps ws footprint at 11.8 MB (round-5's 45 MB overflowed).
    unsigned int* xh = (unsigned int*)d_out;

    char* ws = (char*)d_ws;
    ushort_t*     ws_idx  = (ushort_t*)    (ws + 0);          // 3,145,728 B
    int*          ws_deg  = (int*)         (ws + 3145728);    //     8,192 B
    int*          ws_offs = (int*)         (ws + 3153920);    //     8,192 B
    int*          ws_cur  = (int*)         (ws + 3162112);    //     8,192 B
    ushort_t*     ws_list = (ushort_t*)    (ws + 3170304);    // 3,145,728 B
    unsigned int* ws_eph  = (unsigned int*)(ws + 6316032);    // 1,048,576 B
    float*        ws_wt   = (float*)       (ws + 7364608);    //   262,144 B
    float*        ws_bn1  = (float*)       (ws + 7626752);    // 2,097,152 B
    float*        ws_bn2  = (float*)       (ws + 9723904);    // 2,097,152 B
    float*        ws_ab   = (float*)       (ws + 11821056);   //     2,048 B

    hipMemsetAsync(ws_deg, 0, BB * MM * sizeof(int), stream);
    hipMemsetAsync(ws_cur, 0, BB * MM * sizeof(int), stream);

    hipLaunchKernelGGL(k_cvt,     dim3(32768), dim3(256), 0, stream, x, xh);
    hipLaunchKernelGGL(k_wt,      dim3(256),   dim3(256), 0, stream, fcw, ws_wt);
    hipLaunchKernelGGL(k_topk,    dim3(1024),  dim3(128), 0, stream, coords, anchors, ws_idx, ws_deg);
    hipLaunchKernelGGL(k_offsets, dim3(1),     dim3(256), 0, stream, ws_deg, ws_offs);
    hipLaunchKernelGGL(k_fill,    dim3(256),   dim3(256), 0, stream, ws_idx, ws_offs, ws_cur, ws_list);
    hipLaunchKernelGGL(k_edge2,   dim3(2048),  dim3(256), 0, stream, xh, ws_list, ws_offs, ws_deg, ws_wt, fcb, ws_eph);
    hipLaunchKernelGGL(k_gather,  dim3(2048),  dim3(256), 0, stream, x, (const unsigned int*)ws_idx, ws_eph, out, ws_bn1, ws_bn2);
    hipLaunchKernelGGL(k_stats,   dim3(256),   dim3(256), 0, stream, ws_bn1, ws_bn2, gamma, beta, ws_ab);
    hipLaunchKernelGGL(k_silu,    dim3(16384), dim3(256), 0, stream, out, ws_ab);
}

// Round 7
// 519.300 us; speedup vs baseline: 5.4203x; 1.1946x over previous
//
#include <hip/hip_runtime.h>

#define BB 4
#define NN 16384
#define MM 512
#define CCH 256
#define KNN 24
#define EPSV 1e-5f

typedef unsigned short ushort_t;

__device__ __forceinline__ unsigned int pk_bf16(float a, float b) {
    unsigned int ua = __float_as_uint(a), ub = __float_as_uint(b);
    ua += 0x7FFFu + ((ua >> 16) & 1u);          // RNE to bf16
    ub += 0x7FFFu + ((ub >> 16) & 1u);
    return (ua >> 16) | (ub & 0xFFFF0000u);
}
__device__ __forceinline__ float lo_bf(unsigned int u) { return __uint_as_float(u << 16); }
__device__ __forceinline__ float hi_bf(unsigned int u) { return __uint_as_float(u & 0xFFFF0000u); }

// ---------------- K-1: pack x -> bf16 pairs (uint = 2 channels), lives in d_out ----------------
__global__ __launch_bounds__(256) void k_cvt(const float* __restrict__ x,
                                             unsigned int* __restrict__ xh) {
    int i = blockIdx.x * 256 + threadIdx.x;   // 8,388,608 float2s
    float2 v = ((const float2*)x)[i];
    xh[i] = pk_bf16(v.x, v.y);
}

// ---------------- K0: transpose fc_w (256x256) -> Wt[cin][cout] ----------------
__global__ __launch_bounds__(256) void k_wt(const float* __restrict__ W, float* __restrict__ Wt) {
    int i = blockIdx.x * 256 + threadIdx.x;   // 65536
    int co = i >> 8, ci = i & 255;
    Wt[(ci << 8) + co] = W[i];
}

// ---------------- K1: top-24 nearest anchors, packed-key min/max chain ----------------
// 1024 blocks x 128 threads; lanes l / l+32 split anchors 0-255 / 256-511.
// Candidate key = (order-preserving dist bits & ~511) | anchor_id: sorted-insert
// becomes a 24-step min/max bubble (2 VOP2/step), ids ride in the low bits and
// ties prefer smaller id (= top_k semantics on truncated dist). Named scalars +
// asm "+v" pin keep the list in VGPRs (round-3/6 allocator sent arrays to AGPRs).
#define TKSTEP(K) { unsigned int lo_ = min(ck, K); ck = max(ck, K); K = lo_; }
__global__ __launch_bounds__(128, 2) void k_topk(const float* __restrict__ coords,
                                                 const float* __restrict__ anchors,
                                                 ushort_t* __restrict__ idx_out,
                                                 int* __restrict__ deg) {
    __shared__ float4 alds[MM];     // 8 KB: x,y,z,|a|^2
    __shared__ int    hist[MM];     // 2 KB
    int tid = threadIdx.x;
    int blk = blockIdx.x;           // 1024 blocks: 256 per batch
    int b  = blk >> 8;
    int n0 = (blk & 255) << 6;      // 64 nodes per block
    int lane = tid & 63;
    int half = lane >> 5;           // 0: anchors 0..255, 1: 256..511
    int n = n0 + ((tid >> 6) << 5) + (lane & 31);

    for (int m = tid; m < MM; m += 128) {
        float x_ = anchors[(b * MM + m) * 3 + 0];
        float y_ = anchors[(b * MM + m) * 3 + 1];
        float z_ = anchors[(b * MM + m) * 3 + 2];
        alds[m] = make_float4(x_, y_, z_, x_ * x_ + y_ * y_ + z_ * z_);
        hist[m] = 0;
    }
    __syncthreads();

    float cx = coords[(b * NN + n) * 3 + 0];
    float cy = coords[(b * NN + n) * 3 + 1];
    float cz = coords[(b * NN + n) * 3 + 2];
    float cn2 = cx * cx + cy * cy + cz * cz;

    unsigned int k0 = 0xFFFFFFFFu, k1 = 0xFFFFFFFFu, k2 = 0xFFFFFFFFu, k3 = 0xFFFFFFFFu,
                 k4 = 0xFFFFFFFFu, k5 = 0xFFFFFFFFu, k6 = 0xFFFFFFFFu, k7 = 0xFFFFFFFFu,
                 k8 = 0xFFFFFFFFu, k9 = 0xFFFFFFFFu, k10 = 0xFFFFFFFFu, k11 = 0xFFFFFFFFu,
                 k12 = 0xFFFFFFFFu, k13 = 0xFFFFFFFFu, k14 = 0xFFFFFFFFu, k15 = 0xFFFFFFFFu,
                 k16 = 0xFFFFFFFFu, k17 = 0xFFFFFFFFu, k18 = 0xFFFFFFFFu, k19 = 0xFFFFFFFFu,
                 k20 = 0xFFFFFFFFu, k21 = 0xFFFFFFFFu, k22 = 0xFFFFFFFFu, k23 = 0xFFFFFFFFu;

    int base = half << 8;
    for (int mm = 0; mm < 256; ++mm) {
        float4 a = alds[base + mm];
        float dot = cx * a.x + cy * a.y + cz * a.z;
        float cd = cn2 + a.w - 2.0f * dot;          // same arithmetic as prior rounds
        unsigned int u = __float_as_uint(cd) ^ 0x80000000u;   // order-preserving (nonneg)
        unsigned int ck = (u & 0xFFFFFE00u) | (unsigned int)(base + mm);
        TKSTEP(k0)  TKSTEP(k1)  TKSTEP(k2)  TKSTEP(k3)
        TKSTEP(k4)  TKSTEP(k5)  TKSTEP(k6)  TKSTEP(k7)
        TKSTEP(k8)  TKSTEP(k9)  TKSTEP(k10) TKSTEP(k11)
        TKSTEP(k12) TKSTEP(k13) TKSTEP(k14) TKSTEP(k15)
        TKSTEP(k16) TKSTEP(k17) TKSTEP(k18) TKSTEP(k19)
        TKSTEP(k20) TKSTEP(k21) TKSTEP(k22) TKSTEP(k23)
        asm volatile("" : "+v"(k0), "+v"(k1), "+v"(k2), "+v"(k3), "+v"(k4), "+v"(k5),
                          "+v"(k6), "+v"(k7), "+v"(k8), "+v"(k9), "+v"(k10), "+v"(k11),
                          "+v"(k12), "+v"(k13), "+v"(k14), "+v"(k15), "+v"(k16), "+v"(k17),
                          "+v"(k18), "+v"(k19), "+v"(k20), "+v"(k21), "+v"(k22), "+v"(k23));
    }

    unsigned int kk[24] = {k0, k1, k2, k3, k4, k5, k6, k7, k8, k9, k10, k11,
                           k12, k13, k14, k15, k16, k17, k18, k19, k20, k21, k22, k23};

    // cross-lane merge: global top-24 of A(0-255 side) and B(256-511 side) is the
    // multiset { min(A[i], B[23-i]) }. Lower lane emits i=0..11, upper i=12..23.
    // Packed min does the tie-break (A ids < B ids). Order within 24 is irrelevant.
    int Mi[12];
    #pragma unroll
    for (int j = 0; j < 12; ++j) {
        unsigned int sA = __shfl_xor(kk[23 - j], 32);   // partner's kk[23-j]
        unsigned int sB = __shfl_xor(kk[12 + j], 32);   // partner's kk[12+j]
        unsigned int mi = (half == 0) ? min(kk[j], sA) : min(sB, kk[11 - j]);
        Mi[j] = (int)(mi & 511u);
    }

    #pragma unroll
    for (int j = 0; j < 12; ++j) atomicAdd(&hist[Mi[j]], 1);

    // idx as ushort: node stride 24 ushorts (48B); half offset 12 (24B -> 4B aligned)
    unsigned int* ob = (unsigned int*)(idx_out + (size_t)(b * NN + n) * KNN + half * 12);
    ob[0] = (unsigned)(Mi[0] | (Mi[1] << 16));
    ob[1] = (unsigned)(Mi[2] | (Mi[3] << 16));
    ob[2] = (unsigned)(Mi[4] | (Mi[5] << 16));
    ob[3] = (unsigned)(Mi[6] | (Mi[7] << 16));
    ob[4] = (unsigned)(Mi[8] | (Mi[9] << 16));
    ob[5] = (unsigned)(Mi[10] | (Mi[11] << 16));

    __syncthreads();
    for (int m = tid; m < MM; m += 128) {
        int h = hist[m];
        if (h) atomicAdd(&deg[(b << 9) + m], h);
    }
}

// ---------------- K2a: exclusive prefix sum of deg (2048) -> offs ----------------
__global__ __launch_bounds__(256) void k_offsets(const int* __restrict__ deg,
                                                 int* __restrict__ offs) {
    __shared__ int part[256];
    int t = threadIdx.x;
    int v[8];
    int s = 0;
    #pragma unroll
    for (int j = 0; j < 8; ++j) { v[j] = deg[t * 8 + j]; s += v[j]; }
    part[t] = s;
    __syncthreads();
    for (int off = 1; off < 256; off <<= 1) {
        int val = (t >= off) ? part[t - off] : 0;
        __syncthreads();
        part[t] += val;
        __syncthreads();
    }
    int excl = part[t] - s;
    #pragma unroll
    for (int j = 0; j < 8; ++j) { offs[t * 8 + j] = excl; excl += v[j]; }
}

// ---------------- K2b: fill CSR member lists (node ids per edge, ushort) ----------------
__global__ __launch_bounds__(256) void k_fill(const ushort_t* __restrict__ idxb,
                                              const int* __restrict__ offs,
                                              int* __restrict__ cur,
                                              ushort_t* __restrict__ list) {
    int gn = blockIdx.x * 256 + threadIdx.x;   // 0..65535
    int b = gn >> 14;
    #pragma unroll
    for (int k = 0; k < KNN; ++k) {
        int m = idxb[(size_t)gn * KNN + k];
        int e = (b << 9) + m;
        int p = atomicAdd(&cur[e], 1);
        list[(size_t)offs[e] + p] = (ushort_t)(gn & 16383);
    }
}

// ---------------- K3: E' = ((gather(xh)*inv_e)@W^T + b*(deg>0)) / 24, bf16 out ----------------
__global__ __launch_bounds__(256) void k_edge2(const unsigned int* __restrict__ xh,
                                               const ushort_t* __restrict__ list,
                                               const int* __restrict__ offs,
                                               const int* __restrict__ deg,
                                               const float* __restrict__ Wt,
                                               const float* __restrict__ fcb,
                                               unsigned int* __restrict__ Eph) {
    __shared__ ushort_t nl[256];
    __shared__ float part[2][128][2];
    __shared__ float srow[CCH];
    __shared__ float rrow[CCH];
    int tid = threadIdx.x;
    int blk = blockIdx.x;               // b*512 + m
    int b = blk >> 9;
    int d = deg[blk];
    int o = offs[blk];
    int cp = tid & 127, rs = tid >> 7;  // channel pair, row parity
    const unsigned int* xb = xh + ((size_t)b << 21);   // b * NN * 128

    float l0 = 0.f, l1 = 0.f, l2 = 0.f, l3 = 0.f;
    float h0 = 0.f, h1 = 0.f, h2 = 0.f, h3 = 0.f;
    for (int base2 = 0; base2 < d; base2 += 256) {
        int cnt = min(256, d - base2);
        if (tid < cnt) nl[tid] = list[(size_t)o + base2 + tid];
        __syncthreads();
        int i = 0;
        for (; i + 7 < cnt; i += 8) {
            unsigned int u0 = xb[((size_t)nl[i + 0 + rs] << 7) + cp];
            unsigned int u1 = xb[((size_t)nl[i + 2 + rs] << 7) + cp];
            unsigned int u2 = xb[((size_t)nl[i + 4 + rs] << 7) + cp];
            unsigned int u3 = xb[((size_t)nl[i + 6 + rs] << 7) + cp];
            l0 += lo_bf(u0); h0 += hi_bf(u0);
            l1 += lo_bf(u1); h1 += hi_bf(u1);
            l2 += lo_bf(u2); h2 += hi_bf(u2);
            l3 += lo_bf(u3); h3 += hi_bf(u3);
        }
        for (; i + 1 < cnt; i += 2) {
            unsigned int u = xb[((size_t)nl[i + rs] << 7) + cp];
            l0 += lo_bf(u); h0 += hi_bf(u);
        }
        if (i < cnt && rs == 0) {
            unsigned int u = xb[((size_t)nl[i] << 7) + cp];
            l0 += lo_bf(u); h0 += hi_bf(u);
        }
        __syncthreads();
    }
    part[rs][cp][0] = (l0 + l1) + (l2 + l3);
    part[rs][cp][1] = (h0 + h1) + (h2 + h3);
    __syncthreads();
    float inv = (d > 0) ? (1.0f / (float)d) : 0.0f;
    srow[tid] = (part[0][tid >> 1][tid & 1] + part[1][tid >> 1][tid & 1]) * inv;
    __syncthreads();

    float c0 = (d > 0) ? fcb[tid] : 0.0f;
    float c1 = 0.f, c2 = 0.f, c3 = 0.f;
    #pragma unroll 4
    for (int ci = 0; ci < CCH; ci += 4) {
        c0 = fmaf(srow[ci + 0], Wt[((ci + 0) << 8) + tid], c0);
        c1 = fmaf(srow[ci + 1], Wt[((ci + 1) << 8) + tid], c1);
        c2 = fmaf(srow[ci + 2], Wt[((ci + 2) << 8) + tid], c2);
        c3 = fmaf(srow[ci + 3], Wt[((ci + 3) << 8) + tid], c3);
    }
    rrow[tid] = ((c0 + c1) + (c2 + c3)) * (1.0f / 24.0f);
    __syncthreads();
    if (tid < 128) Eph[(size_t)blk * 128 + tid] = pk_bf16(rrow[2 * tid], rrow[2 * tid + 1]);
}

// ---------------- K4: out = H@E' + x, transposed write + BN partials ----------------
__global__ __launch_bounds__(256) void k_gather(const float* __restrict__ x,
                                                const unsigned int* __restrict__ idxu,
                                                const unsigned int* __restrict__ Eph,
                                                float* __restrict__ out,
                                                float* __restrict__ bn1,
                                                float* __restrict__ bn2) {
    __shared__ int   it[32 * KNN];          // 768 ints
    __shared__ float tile[32][CCH + 1];     // 32 x 257 = 32.9 KB
    int tid = threadIdx.x;
    int blk = blockIdx.x;                   // 2048: b * 512 node-chunks
    int b = blk >> 9;
    int n0 = (blk & 511) << 5;              // 32 nodes
    int cp = tid & 127, rs = tid >> 7;

    for (int i = tid; i < 32 * 12; i += 256) {           // 384 packed uints
        unsigned int u = idxu[(size_t)(b * NN + n0) * 12 + i];
        it[2 * i] = u & 0xFFFF;
        it[2 * i + 1] = u >> 16;
    }
    __syncthreads();

    const unsigned int* Eb = Eph + ((size_t)(b * MM) << 7);
    for (int j2 = 0; j2 < 16; ++j2) {
        int j = 2 * j2 + rs;
        int n = n0 + j;
        const int* itj = &it[j * KNN];
        float al = 0.f, ah = 0.f, bl = 0.f, bh = 0.f;
        float cl = 0.f, ch = 0.f, dl = 0.f, dh = 0.f;
        #pragma unroll
        for (int k = 0; k < KNN; k += 4) {
            unsigned int u0 = Eb[((size_t)itj[k + 0] << 7) + cp];
            unsigned int u1 = Eb[((size_t)itj[k + 1] << 7) + cp];
            unsigned int u2 = Eb[((size_t)itj[k + 2] << 7) + cp];
            unsigned int u3 = Eb[((size_t)itj[k + 3] << 7) + cp];
            al += lo_bf(u0); ah += hi_bf(u0);
            bl += lo_bf(u1); bh += hi_bf(u1);
            cl += lo_bf(u2); ch += hi_bf(u2);
            dl += lo_bf(u3); dh += hi_bf(u3);
        }
        float2 xv = ((const float2*)(x + (((size_t)(b * NN + n)) << 8)))[cp];
        tile[j][2 * cp + 0] = xv.x + ((al + bl) + (cl + dl));
        tile[j][2 * cp + 1] = xv.y + ((ah + bh) + (ch + dh));
    }
    __syncthreads();

    float sum = 0.f, ss = 0.f;
    #pragma unroll 4
    for (int j = 0; j < 32; ++j) {
        float v = tile[j][tid];
        sum += v; ss += v * v;
    }
    bn1[(size_t)blk * 256 + tid] = sum;
    bn2[(size_t)blk * 256 + tid] = ss;

    for (int i = tid; i < CCH * 32; i += 256) {
        int c2 = i >> 5, j2 = i & 31;
        out[(((size_t)(b * CCH + c2)) << 14) + n0 + j2] = tile[j2][c2];
    }
}

// ---------------- K5: finalize BN stats -> a[c], bb[c] ----------------
__global__ __launch_bounds__(256) void k_stats(const float* __restrict__ bn1,
                                               const float* __restrict__ bn2,
                                               const float* __restrict__ gamma,
                                               const float* __restrict__ beta,
                                               float* __restrict__ ab) {
    __shared__ float r1[256], r2[256];
    int c = blockIdx.x;
    int t = threadIdx.x;
    float s1 = 0.f, s2 = 0.f;
    for (int i = t; i < 2048; i += 256) {
        s1 += bn1[i * 256 + c];
        s2 += bn2[i * 256 + c];
    }
    r1[t] = s1; r2[t] = s2;
    __syncthreads();
    for (int o = 128; o > 0; o >>= 1) {
        if (t < o) { r1[t] += r1[t + o]; r2[t] += r2[t + o]; }
        __syncthreads();
    }
    if (t == 0) {
        float mean = r1[0] * (1.0f / 65536.0f);
        float var  = r2[0] * (1.0f / 65536.0f) - mean * mean;
        float istd = rsqrtf(var + EPSV);
        float a = gamma[c] * istd;
        ab[c] = a;
        ab[CCH + c] = beta[c] - mean * a;
    }
}

// ---------------- K6: in-place normalize + SiLU ----------------
__global__ __launch_bounds__(256) void k_silu(float* __restrict__ out,
                                              const float* __restrict__ ab) {
    int i = blockIdx.x * 256 + threadIdx.x;     // float4 index, 4194304 total
    int c = (i >> 12) & 255;
    float a = ab[c], bb = ab[CCH + c];
    float4 v = ((float4*)out)[i];
    float t0 = a * v.x + bb;
    float t1 = a * v.y + bb;
    float t2 = a * v.z + bb;
    float t3 = a * v.w + bb;
    v.x = t0 / (1.0f + __expf(-t0));
    v.y = t1 / (1.0f + __expf(-t1));
    v.z = t2 / (1.0f + __expf(-t2));
    v.w = t3 / (1.0f + __expf(-t3));
    ((float4*)out)[i] = v;
}

extern "C" void kernel_launch(void* const* d_in, const int* in_sizes, int n_in,
                              void* d_out, int out_size, void* d_ws, size_t ws_size,
                              hipStream_t stream) {
    (void)in_sizes; (void)n_in; (void)out_size; (void)ws_size;
    const float* x       = (const float*)d_in[0];
    const float* coords  = (const float*)d_in[1];
    const float* anchors = (const float*)d_in[2];
    const float* fcw     = (const float*)d_in[3];
    const float* fcb     = (const float*)d_in[4];
    const float* gamma   = (const float*)d_in[5];
    const float* beta    = (const float*)d_in[6];
    float* out = (float*)d_out;

    // bf16-packed x lives in d_out (33.5 MB of 67 MB); dead before k_gather
    // overwrites d_out. Keeps ws footprint at 11.8 MB.
    unsigned int* xh = (unsigned int*)d_out;

    char* ws = (char*)d_ws;
    ushort_t*     ws_idx  = (ushort_t*)    (ws + 0);          // 3,145,728 B
    int*          ws_deg  = (int*)         (ws + 3145728);    //     8,192 B
    int*          ws_offs = (int*)         (ws + 3153920);    //     8,192 B
    int*          ws_cur  = (int*)         (ws + 3162112);    //     8,192 B
    ushort_t*     ws_list = (ushort_t*)    (ws + 3170304);    // 3,145,728 B
    unsigned int* ws_eph  = (unsigned int*)(ws + 6316032);    // 1,048,576 B
    float*        ws_wt   = (float*)       (ws + 7364608);    //   262,144 B
    float*        ws_bn1  = (float*)       (ws + 7626752);    // 2,097,152 B
    float*        ws_bn2  = (float*)       (ws + 9723904);    // 2,097,152 B
    float*        ws_ab   = (float*)       (ws + 11821056);   //     2,048 B

    hipMemsetAsync(ws_deg, 0, BB * MM * sizeof(int), stream);
    hipMemsetAsync(ws_cur, 0, BB * MM * sizeof(int), stream);

    hipLaunchKernelGGL(k_cvt,     dim3(32768), dim3(256), 0, stream, x, xh);
    hipLaunchKernelGGL(k_wt,      dim3(256),   dim3(256), 0, stream, fcw, ws_wt);
    hipLaunchKernelGGL(k_topk,    dim3(1024),  dim3(128), 0, stream, coords, anchors, ws_idx, ws_deg);
    hipLaunchKernelGGL(k_offsets, dim3(1),     dim3(256), 0, stream, ws_deg, ws_offs);
    hipLaunchKernelGGL(k_fill,    dim3(256),   dim3(256), 0, stream, ws_idx, ws_offs, ws_cur, ws_list);
    hipLaunchKernelGGL(k_edge2,   dim3(2048),  dim3(256), 0, stream, xh, ws_list, ws_offs, ws_deg, ws_wt, fcb, ws_eph);
    hipLaunchKernelGGL(k_gather,  dim3(2048),  dim3(256), 0, stream, x, (const unsigned int*)ws_idx, ws_eph, out, ws_bn1, ws_bn2);
    hipLaunchKernelGGL(k_stats,   dim3(256),   dim3(256), 0, stream, ws_bn1, ws_bn2, gamma, beta, ws_ab);
    hipLaunchKernelGGL(k_silu,    dim3(16384), dim3(256), 0, stream, out, ws_ab);
}

// Round 8
// 313.589 us; speedup vs baseline: 8.9760x; 1.6560x over previous
//
#include <hip/hip_runtime.h>

#define BB 4
#define NN 16384
#define MM 512
#define CCH 256
#define KNN 24
#define EPSV 1e-5f

typedef unsigned short ushort_t;

__device__ __forceinline__ unsigned int pk_bf16(float a, float b) {
    unsigned int ua = __float_as_uint(a), ub = __float_as_uint(b);
    ua += 0x7FFFu + ((ua >> 16) & 1u);          // RNE to bf16
    ub += 0x7FFFu + ((ub >> 16) & 1u);
    return (ua >> 16) | (ub & 0xFFFF0000u);
}
__device__ __forceinline__ float lo_bf(unsigned int u) { return __uint_as_float(u << 16); }
__device__ __forceinline__ float hi_bf(unsigned int u) { return __uint_as_float(u & 0xFFFF0000u); }

// ---------------- K-1: pack x -> bf16 pairs (uint = 2 channels), lives in d_out ----------------
__global__ __launch_bounds__(256) void k_cvt(const float* __restrict__ x,
                                             unsigned int* __restrict__ xh) {
    int i = blockIdx.x * 256 + threadIdx.x;   // 8,388,608 float2s
    float2 v = ((const float2*)x)[i];
    xh[i] = pk_bf16(v.x, v.y);
}

// ---------------- K0: transpose fc_w (256x256) -> Wt[cin][cout] ----------------
__global__ __launch_bounds__(256) void k_wt(const float* __restrict__ W, float* __restrict__ Wt) {
    int i = blockIdx.x * 256 + threadIdx.x;   // 65536
    int co = i >> 8, ci = i & 255;
    Wt[(ci << 8) + co] = W[i];
}

// ---------------- K1: top-24 nearest anchors, packed-key min/max chain ----------------
// (round-7 proven). Change: per-block histogram now written to histT[b][m][g]
// (counting-sort input); global deg atomics removed (k_scan derives deg).
#define TKSTEP(K) { unsigned int lo_ = min(ck, K); ck = max(ck, K); K = lo_; }
__global__ __launch_bounds__(128, 2) void k_topk(const float* __restrict__ coords,
                                                 const float* __restrict__ anchors,
                                                 ushort_t* __restrict__ idx_out,
                                                 int* __restrict__ histT) {
    __shared__ float4 alds[MM];     // 8 KB: x,y,z,|a|^2
    __shared__ int    hist[MM];     // 2 KB
    int tid = threadIdx.x;
    int blk = blockIdx.x;           // 1024 blocks: 256 per batch
    int b  = blk >> 8;
    int g  = blk & 255;             // 64-node group id within batch
    int n0 = g << 6;
    int lane = tid & 63;
    int half = lane >> 5;           // 0: anchors 0..255, 1: 256..511
    int n = n0 + ((tid >> 6) << 5) + (lane & 31);

    for (int m = tid; m < MM; m += 128) {
        float x_ = anchors[(b * MM + m) * 3 + 0];
        float y_ = anchors[(b * MM + m) * 3 + 1];
        float z_ = anchors[(b * MM + m) * 3 + 2];
        alds[m] = make_float4(x_, y_, z_, x_ * x_ + y_ * y_ + z_ * z_);
        hist[m] = 0;
    }
    __syncthreads();

    float cx = coords[(b * NN + n) * 3 + 0];
    float cy = coords[(b * NN + n) * 3 + 1];
    float cz = coords[(b * NN + n) * 3 + 2];
    float cn2 = cx * cx + cy * cy + cz * cz;

    unsigned int k0 = 0xFFFFFFFFu, k1 = 0xFFFFFFFFu, k2 = 0xFFFFFFFFu, k3 = 0xFFFFFFFFu,
                 k4 = 0xFFFFFFFFu, k5 = 0xFFFFFFFFu, k6 = 0xFFFFFFFFu, k7 = 0xFFFFFFFFu,
                 k8 = 0xFFFFFFFFu, k9 = 0xFFFFFFFFu, k10 = 0xFFFFFFFFu, k11 = 0xFFFFFFFFu,
                 k12 = 0xFFFFFFFFu, k13 = 0xFFFFFFFFu, k14 = 0xFFFFFFFFu, k15 = 0xFFFFFFFFu,
                 k16 = 0xFFFFFFFFu, k17 = 0xFFFFFFFFu, k18 = 0xFFFFFFFFu, k19 = 0xFFFFFFFFu,
                 k20 = 0xFFFFFFFFu, k21 = 0xFFFFFFFFu, k22 = 0xFFFFFFFFu, k23 = 0xFFFFFFFFu;

    int base = half << 8;
    for (int mm = 0; mm < 256; ++mm) {
        float4 a = alds[base + mm];
        float dot = cx * a.x + cy * a.y + cz * a.z;
        float cd = cn2 + a.w - 2.0f * dot;
        unsigned int u = __float_as_uint(cd) ^ 0x80000000u;   // order-preserving (nonneg)
        unsigned int ck = (u & 0xFFFFFE00u) | (unsigned int)(base + mm);
        TKSTEP(k0)  TKSTEP(k1)  TKSTEP(k2)  TKSTEP(k3)
        TKSTEP(k4)  TKSTEP(k5)  TKSTEP(k6)  TKSTEP(k7)
        TKSTEP(k8)  TKSTEP(k9)  TKSTEP(k10) TKSTEP(k11)
        TKSTEP(k12) TKSTEP(k13) TKSTEP(k14) TKSTEP(k15)
        TKSTEP(k16) TKSTEP(k17) TKSTEP(k18) TKSTEP(k19)
        TKSTEP(k20) TKSTEP(k21) TKSTEP(k22) TKSTEP(k23)
        asm volatile("" : "+v"(k0), "+v"(k1), "+v"(k2), "+v"(k3), "+v"(k4), "+v"(k5),
                          "+v"(k6), "+v"(k7), "+v"(k8), "+v"(k9), "+v"(k10), "+v"(k11),
                          "+v"(k12), "+v"(k13), "+v"(k14), "+v"(k15), "+v"(k16), "+v"(k17),
                          "+v"(k18), "+v"(k19), "+v"(k20), "+v"(k21), "+v"(k22), "+v"(k23));
    }

    unsigned int kk[24] = {k0, k1, k2, k3, k4, k5, k6, k7, k8, k9, k10, k11,
                           k12, k13, k14, k15, k16, k17, k18, k19, k20, k21, k22, k23};

    // cross-lane merge: global top-24 = multiset { min(A[i], B[23-i]) }.
    int Mi[12];
    #pragma unroll
    for (int j = 0; j < 12; ++j) {
        unsigned int sA = __shfl_xor(kk[23 - j], 32);
        unsigned int sB = __shfl_xor(kk[12 + j], 32);
        unsigned int mi = (half == 0) ? min(kk[j], sA) : min(sB, kk[11 - j]);
        Mi[j] = (int)(mi & 511u);
    }

    #pragma unroll
    for (int j = 0; j < 12; ++j) atomicAdd(&hist[Mi[j]], 1);

    unsigned int* ob = (unsigned int*)(idx_out + (size_t)(b * NN + n) * KNN + half * 12);
    ob[0] = (unsigned)(Mi[0] | (Mi[1] << 16));
    ob[1] = (unsigned)(Mi[2] | (Mi[3] << 16));
    ob[2] = (unsigned)(Mi[4] | (Mi[5] << 16));
    ob[3] = (unsigned)(Mi[6] | (Mi[7] << 16));
    ob[4] = (unsigned)(Mi[8] | (Mi[9] << 16));
    ob[5] = (unsigned)(Mi[10] | (Mi[11] << 16));

    __syncthreads();
    // counting-sort input: histT[((b*512)+m)*256 + g]
    for (int m = tid; m < MM; m += 128)
        histT[((((b << 9) + m)) << 8) + g] = hist[m];
}

// ---------------- K1b: per-edge scan over the 256 groups -> posT, deg ----------------
__global__ __launch_bounds__(64) void k_scan(const int* __restrict__ histT,
                                             int* __restrict__ posT,
                                             int* __restrict__ deg) {
    int e = blockIdx.x;             // 2048 = (b<<9)+m
    int t = threadIdx.x;
    int4 v = ((const int4*)(histT + (e << 8)))[t];   // 4 consecutive g per lane
    int s = v.x + v.y + v.z + v.w;
    int inc = s;
    #pragma unroll
    for (int off = 1; off < 64; off <<= 1) {
        int u = __shfl_up(inc, off);
        if (t >= off) inc += u;
    }
    int excl = inc - s;
    int4 o;
    o.x = excl; o.y = excl + v.x; o.z = o.y + v.y; o.w = o.z + v.z;
    ((int4*)(posT + (e << 8)))[t] = o;
    if (t == 63) deg[e] = inc;
}

// ---------------- K2a: exclusive prefix sum of deg (2048) -> offs ----------------
__global__ __launch_bounds__(256) void k_offsets(const int* __restrict__ deg,
                                                 int* __restrict__ offs) {
    __shared__ int part[256];
    int t = threadIdx.x;
    int v[8];
    int s = 0;
    #pragma unroll
    for (int j = 0; j < 8; ++j) { v[j] = deg[t * 8 + j]; s += v[j]; }
    part[t] = s;
    __syncthreads();
    for (int off = 1; off < 256; off <<= 1) {
        int val = (t >= off) ? part[t - off] : 0;
        __syncthreads();
        part[t] += val;
        __syncthreads();
    }
    int excl = part[t] - s;
    #pragma unroll
    for (int j = 0; j < 8; ++j) { offs[t * 8 + j] = excl; excl += v[j]; }
}

// ---------------- K2b: counting-sort scatter (LDS cursors, no global atomics) ----------------
__global__ __launch_bounds__(256) void k_fill2(const unsigned int* __restrict__ idxu,
                                               const int* __restrict__ posT,
                                               const int* __restrict__ offs,
                                               ushort_t* __restrict__ list) {
    __shared__ int pos[MM];
    __shared__ unsigned int ebuf[768];      // 64 nodes x 12 packed uints
    int tid = threadIdx.x;
    int blk = blockIdx.x;                   // 1024 = (b<<8)+g
    int b = blk >> 8, g = blk & 255;
    int n0 = g << 6;

    for (int m = tid; m < MM; m += 256) {
        int e = (b << 9) + m;
        pos[m] = offs[e] + posT[(e << 8) + g];
    }
    for (int i = tid; i < 768; i += 256)
        ebuf[i] = idxu[(size_t)(b * NN + n0) * 12 + i];
    __syncthreads();

    for (int i = tid; i < 768; i += 256) {
        unsigned int u = ebuf[i];
        int node = n0 + (i / 12);
        int p0 = atomicAdd(&pos[u & 0xFFFFu], 1);
        list[p0] = (ushort_t)node;
        int p1 = atomicAdd(&pos[u >> 16], 1);
        list[p1] = (ushort_t)node;
    }
}

// ---------------- K3: E' = ((gather(xh)*inv_e)@W^T + b*(deg>0)) / 24, bf16 out ----------------
__global__ __launch_bounds__(256) void k_edge2(const unsigned int* __restrict__ xh,
                                               const ushort_t* __restrict__ list,
                                               const int* __restrict__ offs,
                                               const int* __restrict__ deg,
                                               const float* __restrict__ Wt,
                                               const float* __restrict__ fcb,
                                               unsigned int* __restrict__ Eph) {
    __shared__ ushort_t nl[256];
    __shared__ float part[2][128][2];
    __shared__ float srow[CCH];
    __shared__ float rrow[CCH];
    int tid = threadIdx.x;
    int blk = blockIdx.x;               // b*512 + m
    int b = blk >> 9;
    int d = deg[blk];
    int o = offs[blk];
    int cp = tid & 127, rs = tid >> 7;  // channel pair, row parity
    const unsigned int* xb = xh + ((size_t)b << 21);   // b * NN * 128

    float l0 = 0.f, l1 = 0.f, l2 = 0.f, l3 = 0.f;
    float h0 = 0.f, h1 = 0.f, h2 = 0.f, h3 = 0.f;
    for (int base2 = 0; base2 < d; base2 += 256) {
        int cnt = min(256, d - base2);
        if (tid < cnt) nl[tid] = list[(size_t)o + base2 + tid];
        __syncthreads();
        int i = 0;
        for (; i + 7 < cnt; i += 8) {
            unsigned int u0 = xb[((size_t)nl[i + 0 + rs] << 7) + cp];
            unsigned int u1 = xb[((size_t)nl[i + 2 + rs] << 7) + cp];
            unsigned int u2 = xb[((size_t)nl[i + 4 + rs] << 7) + cp];
            unsigned int u3 = xb[((size_t)nl[i + 6 + rs] << 7) + cp];
            l0 += lo_bf(u0); h0 += hi_bf(u0);
            l1 += lo_bf(u1); h1 += hi_bf(u1);
            l2 += lo_bf(u2); h2 += hi_bf(u2);
            l3 += lo_bf(u3); h3 += hi_bf(u3);
        }
        for (; i + 1 < cnt; i += 2) {
            unsigned int u = xb[((size_t)nl[i + rs] << 7) + cp];
            l0 += lo_bf(u); h0 += hi_bf(u);
        }
        if (i < cnt && rs == 0) {
            unsigned int u = xb[((size_t)nl[i] << 7) + cp];
            l0 += lo_bf(u); h0 += hi_bf(u);
        }
        __syncthreads();
    }
    part[rs][cp][0] = (l0 + l1) + (l2 + l3);
    part[rs][cp][1] = (h0 + h1) + (h2 + h3);
    __syncthreads();
    float inv = (d > 0) ? (1.0f / (float)d) : 0.0f;
    srow[tid] = (part[0][tid >> 1][tid & 1] + part[1][tid >> 1][tid & 1]) * inv;
    __syncthreads();

    float c0 = (d > 0) ? fcb[tid] : 0.0f;
    float c1 = 0.f, c2 = 0.f, c3 = 0.f;
    #pragma unroll 4
    for (int ci = 0; ci < CCH; ci += 4) {
        c0 = fmaf(srow[ci + 0], Wt[((ci + 0) << 8) + tid], c0);
        c1 = fmaf(srow[ci + 1], Wt[((ci + 1) << 8) + tid], c1);
        c2 = fmaf(srow[ci + 2], Wt[((ci + 2) << 8) + tid], c2);
        c3 = fmaf(srow[ci + 3], Wt[((ci + 3) << 8) + tid], c3);
    }
    rrow[tid] = ((c0 + c1) + (c2 + c3)) * (1.0f / 24.0f);
    __syncthreads();
    if (tid < 128) Eph[(size_t)blk * 128 + tid] = pk_bf16(rrow[2 * tid], rrow[2 * tid + 1]);
}

// ---------------- K4: out = H@E' + x, transposed write + BN partials ----------------
__global__ __launch_bounds__(256) void k_gather(const float* __restrict__ x,
                                                const unsigned int* __restrict__ idxu,
                                                const unsigned int* __restrict__ Eph,
                                                float* __restrict__ out,
                                                float* __restrict__ bn1,
                                                float* __restrict__ bn2) {
    __shared__ int   it[32 * KNN];          // 768 ints
    __shared__ float tile[32][CCH + 1];     // 32 x 257 = 32.9 KB
    int tid = threadIdx.x;
    int blk = blockIdx.x;                   // 2048: b * 512 node-chunks
    int b = blk >> 9;
    int n0 = (blk & 511) << 5;              // 32 nodes
    int cp = tid & 127, rs = tid >> 7;

    for (int i = tid; i < 32 * 12; i += 256) {           // 384 packed uints
        unsigned int u = idxu[(size_t)(b * NN + n0) * 12 + i];
        it[2 * i] = u & 0xFFFF;
        it[2 * i + 1] = u >> 16;
    }
    __syncthreads();

    const unsigned int* Eb = Eph + ((size_t)(b * MM) << 7);
    for (int j2 = 0; j2 < 16; ++j2) {
        int j = 2 * j2 + rs;
        int n = n0 + j;
        const int* itj = &it[j * KNN];
        float al = 0.f, ah = 0.f, bl = 0.f, bh = 0.f;
        float cl = 0.f, ch = 0.f, dl = 0.f, dh = 0.f;
        #pragma unroll
        for (int k = 0; k < KNN; k += 4) {
            unsigned int u0 = Eb[((size_t)itj[k + 0] << 7) + cp];
            unsigned int u1 = Eb[((size_t)itj[k + 1] << 7) + cp];
            unsigned int u2 = Eb[((size_t)itj[k + 2] << 7) + cp];
            unsigned int u3 = Eb[((size_t)itj[k + 3] << 7) + cp];
            al += lo_bf(u0); ah += hi_bf(u0);
            bl += lo_bf(u1); bh += hi_bf(u1);
            cl += lo_bf(u2); ch += hi_bf(u2);
            dl += lo_bf(u3); dh += hi_bf(u3);
        }
        float2 xv = ((const float2*)(x + (((size_t)(b * NN + n)) << 8)))[cp];
        tile[j][2 * cp + 0] = xv.x + ((al + bl) + (cl + dl));
        tile[j][2 * cp + 1] = xv.y + ((ah + bh) + (ch + dh));
    }
    __syncthreads();

    float sum = 0.f, ss = 0.f;
    #pragma unroll 4
    for (int j = 0; j < 32; ++j) {
        float v = tile[j][tid];
        sum += v; ss += v * v;
    }
    bn1[(size_t)blk * 256 + tid] = sum;
    bn2[(size_t)blk * 256 + tid] = ss;

    for (int i = tid; i < CCH * 32; i += 256) {
        int c2 = i >> 5, j2 = i & 31;
        out[(((size_t)(b * CCH + c2)) << 14) + n0 + j2] = tile[j2][c2];
    }
}

// ---------------- K5: finalize BN stats -> a[c], bb[c] ----------------
__global__ __launch_bounds__(256) void k_stats(const float* __restrict__ bn1,
                                               const float* __restrict__ bn2,
                                               const float* __restrict__ gamma,
                                               const float* __restrict__ beta,
                                               float* __restrict__ ab) {
    __shared__ float r1[256], r2[256];
    int c = blockIdx.x;
    int t = threadIdx.x;
    float s1 = 0.f, s2 = 0.f;
    for (int i = t; i < 2048; i += 256) {
        s1 += bn1[i * 256 + c];
        s2 += bn2[i * 256 + c];
    }
    r1[t] = s1; r2[t] = s2;
    __syncthreads();
    for (int o = 128; o > 0; o >>= 1) {
        if (t < o) { r1[t] += r1[t + o]; r2[t] += r2[t + o]; }
        __syncthreads();
    }
    if (t == 0) {
        float mean = r1[0] * (1.0f / 65536.0f);
        float var  = r2[0] * (1.0f / 65536.0f) - mean * mean;
        float istd = rsqrtf(var + EPSV);
        float a = gamma[c] * istd;
        ab[c] = a;
        ab[CCH + c] = beta[c] - mean * a;
    }
}

// ---------------- K6: in-place normalize + SiLU ----------------
__global__ __launch_bounds__(256) void k_silu(float* __restrict__ out,
                                              const float* __restrict__ ab) {
    int i = blockIdx.x * 256 + threadIdx.x;     // float4 index, 4194304 total
    int c = (i >> 12) & 255;
    float a = ab[c], bb = ab[CCH + c];
    float4 v = ((float4*)out)[i];
    float t0 = a * v.x + bb;
    float t1 = a * v.y + bb;
    float t2 = a * v.z + bb;
    float t3 = a * v.w + bb;
    v.x = t0 / (1.0f + __expf(-t0));
    v.y = t1 / (1.0f + __expf(-t1));
    v.z = t2 / (1.0f + __expf(-t2));
    v.w = t3 / (1.0f + __expf(-t3));
    ((float4*)out)[i] = v;
}

extern "C" void kernel_launch(void* const* d_in, const int* in_sizes, int n_in,
                              void* d_out, int out_size, void* d_ws, size_t ws_size,
                              hipStream_t stream) {
    (void)in_sizes; (void)n_in; (void)out_size; (void)ws_size;
    const float* x       = (const float*)d_in[0];
    const float* coords  = (const float*)d_in[1];
    const float* anchors = (const float*)d_in[2];
    const float* fcw     = (const float*)d_in[3];
    const float* fcb     = (const float*)d_in[4];
    const float* gamma   = (const float*)d_in[5];
    const float* beta    = (const float*)d_in[6];
    float* out = (float*)d_out;

    // bf16-packed x lives in d_out (33.5 MB of 67 MB); dead before k_gather
    // overwrites d_out. ws footprint 16.0 MB (< proven-safe 19.2 MB).
    unsigned int* xh = (unsigned int*)d_out;

    char* ws = (char*)d_ws;
    ushort_t*     ws_idx   = (ushort_t*)    (ws + 0);          // 3,145,728 B
    int*          ws_deg   = (int*)         (ws + 3145728);    //     8,192 B
    int*          ws_offs  = (int*)         (ws + 3153920);    //     8,192 B
    ushort_t*     ws_list  = (ushort_t*)    (ws + 3162112);    // 3,145,728 B
    int*          ws_histT = (int*)         (ws + 6307840);    // 2,097,152 B
    int*          ws_posT  = (int*)         (ws + 8404992);    // 2,097,152 B
    unsigned int* ws_eph   = (unsigned int*)(ws + 10502144);   // 1,048,576 B
    float*        ws_wt    = (float*)       (ws + 11550720);   //   262,144 B
    float*        ws_bn1   = (float*)       (ws + 11812864);   // 2,097,152 B
    float*        ws_bn2   = (float*)       (ws + 13910016);   // 2,097,152 B
    float*        ws_ab    = (float*)       (ws + 16007168);   //     2,048 B

    hipLaunchKernelGGL(k_cvt,     dim3(32768), dim3(256), 0, stream, x, xh);
    hipLaunchKernelGGL(k_wt,      dim3(256),   dim3(256), 0, stream, fcw, ws_wt);
    hipLaunchKernelGGL(k_topk,    dim3(1024),  dim3(128), 0, stream, coords, anchors, ws_idx, ws_histT);
    hipLaunchKernelGGL(k_scan,    dim3(2048),  dim3(64),  0, stream, ws_histT, ws_posT, ws_deg);
    hipLaunchKernelGGL(k_offsets, dim3(1),     dim3(256), 0, stream, ws_deg, ws_offs);
    hipLaunchKernelGGL(k_fill2,   dim3(1024),  dim3(256), 0, stream, (const unsigned int*)ws_idx, ws_posT, ws_offs, ws_list);
    hipLaunchKernelGGL(k_edge2,   dim3(2048),  dim3(256), 0, stream, xh, ws_list, ws_offs, ws_deg, ws_wt, fcb, ws_eph);
    hipLaunchKernelGGL(k_gather,  dim3(2048),  dim3(256), 0, stream, x, (const unsigned int*)ws_idx, ws_eph, out, ws_bn1, ws_bn2);
    hipLaunchKernelGGL(k_stats,   dim3(256),   dim3(256), 0, stream, ws_bn1, ws_bn2, gamma, beta, ws_ab);
    hipLaunchKernelGGL(k_silu,    dim3(16384), dim3(256), 0, stream, out, ws_ab);
}

// Round 9
// 309.623 us; speedup vs baseline: 9.0910x; 1.0128x over previous
//
#include <hip/hip_runtime.h>

#define BB 4
#define NN 16384
#define MM 512
#define CCH 256
#define KNN 24
#define EPSV 1e-5f

typedef unsigned short ushort_t;

__device__ __forceinline__ unsigned int pk_bf16(float a, float b) {
    unsigned int ua = __float_as_uint(a), ub = __float_as_uint(b);
    ua += 0x7FFFu + ((ua >> 16) & 1u);          // RNE to bf16
    ub += 0x7FFFu + ((ub >> 16) & 1u);
    return (ua >> 16) | (ub & 0xFFFF0000u);
}
__device__ __forceinline__ float lo_bf(unsigned int u) { return __uint_as_float(u << 16); }
__device__ __forceinline__ float hi_bf(unsigned int u) { return __uint_as_float(u & 0xFFFF0000u); }

// ---------------- K-1: pack x -> bf16 pairs (uint = 2 channels), lives in d_out ----------------
__global__ __launch_bounds__(256) void k_cvt(const float* __restrict__ x,
                                             unsigned int* __restrict__ xh) {
    int i = blockIdx.x * 256 + threadIdx.x;   // 8,388,608 float2s
    float2 v = ((const float2*)x)[i];
    xh[i] = pk_bf16(v.x, v.y);
}

// ---------------- K0: transpose fc_w (256x256) -> Wt[cin][cout] ----------------
__global__ __launch_bounds__(256) void k_wt(const float* __restrict__ W, float* __restrict__ Wt) {
    int i = blockIdx.x * 256 + threadIdx.x;   // 65536
    int co = i >> 8, ci = i & 255;
    Wt[(ci << 8) + co] = W[i];
}

// ---------------- K1: top-24, packed keys, full chain in ONE asm block ----------------
// Bubble step j: t=min(c,kj); c=max(c,kj); kj=t  (3 inst). Two candidates A,B are
// software-pipelined through the same list staggered one stage (A.s0,[B.s0,A.s1],
// ...,B.s23): every dep pair is >=3 inst (6 cyc) apart -> no VALU stalls, and the
// single asm block forces arch-VGPR residence (round-8: AGPR shuttle = 159 inst/cand).
// Interleave == sequential insert (B reads kj strictly after A's stage-j update).
#define SOP(J, C, T) \
    "v_min_u32 %" #T ", %" #C ", %" #J "\n\t" \
    "v_max_u32 %" #C ", %" #C ", %" #J "\n\t" \
    "v_mov_b32 %" #J ", %" #T "\n\t"
__global__ __launch_bounds__(128, 2) void k_topk(const float* __restrict__ coords,
                                                 const float* __restrict__ anchors,
                                                 ushort_t* __restrict__ idx_out,
                                                 int* __restrict__ histT) {
    __shared__ float4 alds[MM];     // 8 KB: x,y,z,|a|^2
    __shared__ int    hist[MM];     // 2 KB
    int tid = threadIdx.x;
    int blk = blockIdx.x;           // 1024 blocks: 256 per batch
    int b  = blk >> 8;
    int g  = blk & 255;             // 64-node group id within batch
    int n0 = g << 6;
    int lane = tid & 63;
    int half = lane >> 5;           // 0: anchors 0..255, 1: 256..511
    int n = n0 + ((tid >> 6) << 5) + (lane & 31);

    for (int m = tid; m < MM; m += 128) {
        float x_ = anchors[(b * MM + m) * 3 + 0];
        float y_ = anchors[(b * MM + m) * 3 + 1];
        float z_ = anchors[(b * MM + m) * 3 + 2];
        alds[m] = make_float4(x_, y_, z_, x_ * x_ + y_ * y_ + z_ * z_);
        hist[m] = 0;
    }
    __syncthreads();

    float cx = coords[(b * NN + n) * 3 + 0];
    float cy = coords[(b * NN + n) * 3 + 1];
    float cz = coords[(b * NN + n) * 3 + 2];
    float cn2 = cx * cx + cy * cy + cz * cz;

    unsigned int k0 = 0xFFFFFFFFu, k1 = 0xFFFFFFFFu, k2 = 0xFFFFFFFFu, k3 = 0xFFFFFFFFu,
                 k4 = 0xFFFFFFFFu, k5 = 0xFFFFFFFFu, k6 = 0xFFFFFFFFu, k7 = 0xFFFFFFFFu,
                 k8 = 0xFFFFFFFFu, k9 = 0xFFFFFFFFu, k10 = 0xFFFFFFFFu, k11 = 0xFFFFFFFFu,
                 k12 = 0xFFFFFFFFu, k13 = 0xFFFFFFFFu, k14 = 0xFFFFFFFFu, k15 = 0xFFFFFFFFu,
                 k16 = 0xFFFFFFFFu, k17 = 0xFFFFFFFFu, k18 = 0xFFFFFFFFu, k19 = 0xFFFFFFFFu,
                 k20 = 0xFFFFFFFFu, k21 = 0xFFFFFFFFu, k22 = 0xFFFFFFFFu, k23 = 0xFFFFFFFFu;

    int base = half << 8;
    for (int mm = 0; mm < 128; ++mm) {
        float4 a0 = alds[base + 2 * mm];
        float4 a1 = alds[base + 2 * mm + 1];
        float cd0 = cn2 + a0.w - 2.0f * (cx * a0.x + cy * a0.y + cz * a0.z);
        float cd1 = cn2 + a1.w - 2.0f * (cx * a1.x + cy * a1.y + cz * a1.z);
        unsigned int u0 = __float_as_uint(cd0) ^ 0x80000000u;   // order-preserving (nonneg)
        unsigned int u1 = __float_as_uint(cd1) ^ 0x80000000u;
        unsigned int cA = (u0 & 0xFFFFFE00u) | (unsigned int)(base + 2 * mm);
        unsigned int cB = (u1 & 0xFFFFFE00u) | (unsigned int)(base + 2 * mm + 1);
        unsigned int tA, tB;
        asm volatile(
            SOP(0, 24, 26)
            SOP(0, 25, 27)  SOP(1, 24, 26)
            SOP(1, 25, 27)  SOP(2, 24, 26)
            SOP(2, 25, 27)  SOP(3, 24, 26)
            SOP(3, 25, 27)  SOP(4, 24, 26)
            SOP(4, 25, 27)  SOP(5, 24, 26)
            SOP(5, 25, 27)  SOP(6, 24, 26)
            SOP(6, 25, 27)  SOP(7, 24, 26)
            SOP(7, 25, 27)  SOP(8, 24, 26)
            SOP(8, 25, 27)  SOP(9, 24, 26)
            SOP(9, 25, 27)  SOP(10, 24, 26)
            SOP(10, 25, 27) SOP(11, 24, 26)
            SOP(11, 25, 27) SOP(12, 24, 26)
            SOP(12, 25, 27) SOP(13, 24, 26)
            SOP(13, 25, 27) SOP(14, 24, 26)
            SOP(14, 25, 27) SOP(15, 24, 26)
            SOP(15, 25, 27) SOP(16, 24, 26)
            SOP(16, 25, 27) SOP(17, 24, 26)
            SOP(17, 25, 27) SOP(18, 24, 26)
            SOP(18, 25, 27) SOP(19, 24, 26)
            SOP(19, 25, 27) SOP(20, 24, 26)
            SOP(20, 25, 27) SOP(21, 24, 26)
            SOP(21, 25, 27) SOP(22, 24, 26)
            SOP(22, 25, 27) SOP(23, 24, 26)
            SOP(23, 25, 27)
            : "+v"(k0), "+v"(k1), "+v"(k2), "+v"(k3), "+v"(k4), "+v"(k5),
              "+v"(k6), "+v"(k7), "+v"(k8), "+v"(k9), "+v"(k10), "+v"(k11),
              "+v"(k12), "+v"(k13), "+v"(k14), "+v"(k15), "+v"(k16), "+v"(k17),
              "+v"(k18), "+v"(k19), "+v"(k20), "+v"(k21), "+v"(k22), "+v"(k23),
              "+v"(cA), "+v"(cB), "=&v"(tA), "=&v"(tB));
    }

    unsigned int kk[24] = {k0, k1, k2, k3, k4, k5, k6, k7, k8, k9, k10, k11,
                           k12, k13, k14, k15, k16, k17, k18, k19, k20, k21, k22, k23};

    // cross-lane merge: global top-24 = multiset { min(A[i], B[23-i]) }.
    int Mi[12];
    #pragma unroll
    for (int j = 0; j < 12; ++j) {
        unsigned int sA = __shfl_xor(kk[23 - j], 32);
        unsigned int sB = __shfl_xor(kk[12 + j], 32);
        unsigned int mi = (half == 0) ? min(kk[j], sA) : min(sB, kk[11 - j]);
        Mi[j] = (int)(mi & 511u);
    }

    #pragma unroll
    for (int j = 0; j < 12; ++j) atomicAdd(&hist[Mi[j]], 1);

    unsigned int* ob = (unsigned int*)(idx_out + (size_t)(b * NN + n) * KNN + half * 12);
    ob[0] = (unsigned)(Mi[0] | (Mi[1] << 16));
    ob[1] = (unsigned)(Mi[2] | (Mi[3] << 16));
    ob[2] = (unsigned)(Mi[4] | (Mi[5] << 16));
    ob[3] = (unsigned)(Mi[6] | (Mi[7] << 16));
    ob[4] = (unsigned)(Mi[8] | (Mi[9] << 16));
    ob[5] = (unsigned)(Mi[10] | (Mi[11] << 16));

    __syncthreads();
    // counting-sort input: histT[((b*512)+m)*256 + g]
    for (int m = tid; m < MM; m += 128)
        histT[((((b << 9) + m)) << 8) + g] = hist[m];
}

// ---------------- K1b: per-edge scan over the 256 groups -> posT, deg ----------------
__global__ __launch_bounds__(64) void k_scan(const int* __restrict__ histT,
                                             int* __restrict__ posT,
                                             int* __restrict__ deg) {
    int e = blockIdx.x;             // 2048 = (b<<9)+m
    int t = threadIdx.x;
    int4 v = ((const int4*)(histT + (e << 8)))[t];   // 4 consecutive g per lane
    int s = v.x + v.y + v.z + v.w;
    int inc = s;
    #pragma unroll
    for (int off = 1; off < 64; off <<= 1) {
        int u = __shfl_up(inc, off);
        if (t >= off) inc += u;
    }
    int excl = inc - s;
    int4 o;
    o.x = excl; o.y = excl + v.x; o.z = o.y + v.y; o.w = o.z + v.z;
    ((int4*)(posT + (e << 8)))[t] = o;
    if (t == 63) deg[e] = inc;
}

// ---------------- K2a: exclusive prefix sum of deg (2048) -> offs ----------------
__global__ __launch_bounds__(256) void k_offsets(const int* __restrict__ deg,
                                                 int* __restrict__ offs) {
    __shared__ int part[256];
    int t = threadIdx.x;
    int v[8];
    int s = 0;
    #pragma unroll
    for (int j = 0; j < 8; ++j) { v[j] = deg[t * 8 + j]; s += v[j]; }
    part[t] = s;
    __syncthreads();
    for (int off = 1; off < 256; off <<= 1) {
        int val = (t >= off) ? part[t - off] : 0;
        __syncthreads();
        part[t] += val;
        __syncthreads();
    }
    int excl = part[t] - s;
    #pragma unroll
    for (int j = 0; j < 8; ++j) { offs[t * 8 + j] = excl; excl += v[j]; }
}

// ---------------- K2b: counting-sort scatter (LDS cursors, no global atomics) ----------------
__global__ __launch_bounds__(256) void k_fill2(const unsigned int* __restrict__ idxu,
                                               const int* __restrict__ posT,
                                               const int* __restrict__ offs,
                                               ushort_t* __restrict__ list) {
    __shared__ int pos[MM];
    __shared__ unsigned int ebuf[768];      // 64 nodes x 12 packed uints
    int tid = threadIdx.x;
    int blk = blockIdx.x;                   // 1024 = (b<<8)+g
    int b = blk >> 8, g = blk & 255;
    int n0 = g << 6;

    for (int m = tid; m < MM; m += 256) {
        int e = (b << 9) + m;
        pos[m] = offs[e] + posT[(e << 8) + g];
    }
    for (int i = tid; i < 768; i += 256)
        ebuf[i] = idxu[(size_t)(b * NN + n0) * 12 + i];
    __syncthreads();

    for (int i = tid; i < 768; i += 256) {
        unsigned int u = ebuf[i];
        int node = n0 + (i / 12);
        int p0 = atomicAdd(&pos[u & 0xFFFFu], 1);
        list[p0] = (ushort_t)node;
        int p1 = atomicAdd(&pos[u >> 16], 1);
        list[p1] = (ushort_t)node;
    }
}

// ---------------- K3: E' = ((gather(xh)*inv_e)@W^T + b*(deg>0)) / 24, bf16 out ----------------
__global__ __launch_bounds__(256) void k_edge2(const unsigned int* __restrict__ xh,
                                               const ushort_t* __restrict__ list,
                                               const int* __restrict__ offs,
                                               const int* __restrict__ deg,
                                               const float* __restrict__ Wt,
                                               const float* __restrict__ fcb,
                                               unsigned int* __restrict__ Eph) {
    __shared__ ushort_t nl[256];
    __shared__ float part[2][128][2];
    __shared__ float srow[CCH];
    __shared__ float rrow[CCH];
    int tid = threadIdx.x;
    int blk = blockIdx.x;               // b*512 + m
    int b = blk >> 9;
    int d = deg[blk];
    int o = offs[blk];
    int cp = tid & 127, rs = tid >> 7;  // channel pair, row parity
    const unsigned int* xb = xh + ((size_t)b << 21);   // b * NN * 128

    float l0 = 0.f, l1 = 0.f, l2 = 0.f, l3 = 0.f;
    float h0 = 0.f, h1 = 0.f, h2 = 0.f, h3 = 0.f;
    for (int base2 = 0; base2 < d; base2 += 256) {
        int cnt = min(256, d - base2);
        if (tid < cnt) nl[tid] = list[(size_t)o + base2 + tid];
        __syncthreads();
        int i = 0;
        for (; i + 7 < cnt; i += 8) {
            unsigned int u0 = xb[((size_t)nl[i + 0 + rs] << 7) + cp];
            unsigned int u1 = xb[((size_t)nl[i + 2 + rs] << 7) + cp];
            unsigned int u2 = xb[((size_t)nl[i + 4 + rs] << 7) + cp];
            unsigned int u3 = xb[((size_t)nl[i + 6 + rs] << 7) + cp];
            l0 += lo_bf(u0); h0 += hi_bf(u0);
            l1 += lo_bf(u1); h1 += hi_bf(u1);
            l2 += lo_bf(u2); h2 += hi_bf(u2);
            l3 += lo_bf(u3); h3 += hi_bf(u3);
        }
        for (; i + 1 < cnt; i += 2) {
            unsigned int u = xb[((size_t)nl[i + rs] << 7) + cp];
            l0 += lo_bf(u); h0 += hi_bf(u);
        }
        if (i < cnt && rs == 0) {
            unsigned int u = xb[((size_t)nl[i] << 7) + cp];
            l0 += lo_bf(u); h0 += hi_bf(u);
        }
        __syncthreads();
    }
    part[rs][cp][0] = (l0 + l1) + (l2 + l3);
    part[rs][cp][1] = (h0 + h1) + (h2 + h3);
    __syncthreads();
    float inv = (d > 0) ? (1.0f / (float)d) : 0.0f;
    srow[tid] = (part[0][tid >> 1][tid & 1] + part[1][tid >> 1][tid & 1]) * inv;
    __syncthreads();

    float c0 = (d > 0) ? fcb[tid] : 0.0f;
    float c1 = 0.f, c2 = 0.f, c3 = 0.f;
    #pragma unroll 4
    for (int ci = 0; ci < CCH; ci += 4) {
        c0 = fmaf(srow[ci + 0], Wt[((ci + 0) << 8) + tid], c0);
        c1 = fmaf(srow[ci + 1], Wt[((ci + 1) << 8) + tid], c1);
        c2 = fmaf(srow[ci + 2], Wt[((ci + 2) << 8) + tid], c2);
        c3 = fmaf(srow[ci + 3], Wt[((ci + 3) << 8) + tid], c3);
    }
    rrow[tid] = ((c0 + c1) + (c2 + c3)) * (1.0f / 24.0f);
    __syncthreads();
    if (tid < 128) Eph[(size_t)blk * 128 + tid] = pk_bf16(rrow[2 * tid], rrow[2 * tid + 1]);
}

// ---------------- K4: out = H@E' + x, transposed write + BN partials ----------------
__global__ __launch_bounds__(256) void k_gather(const float* __restrict__ x,
                                                const unsigned int* __restrict__ idxu,
                                                const unsigned int* __restrict__ Eph,
                                                float* __restrict__ out,
                                                float* __restrict__ bn1,
                                                float* __restrict__ bn2) {
    __shared__ int   it[32 * KNN];          // 768 ints
    __shared__ float tile[32][CCH + 1];     // 32 x 257 = 32.9 KB
    int tid = threadIdx.x;
    int blk = blockIdx.x;                   // 2048: b * 512 node-chunks
    int b = blk >> 9;
    int n0 = (blk & 511) << 5;              // 32 nodes
    int cp = tid & 127, rs = tid >> 7;

    for (int i = tid; i < 32 * 12; i += 256) {           // 384 packed uints
        unsigned int u = idxu[(size_t)(b * NN + n0) * 12 + i];
        it[2 * i] = u & 0xFFFF;
        it[2 * i + 1] = u >> 16;
    }
    __syncthreads();

    const unsigned int* Eb = Eph + ((size_t)(b * MM) << 7);
    for (int j2 = 0; j2 < 16; ++j2) {
        int j = 2 * j2 + rs;
        int n = n0 + j;
        const int* itj = &it[j * KNN];
        float al = 0.f, ah = 0.f, bl = 0.f, bh = 0.f;
        float cl = 0.f, ch = 0.f, dl = 0.f, dh = 0.f;
        #pragma unroll
        for (int k = 0; k < KNN; k += 4) {
            unsigned int u0 = Eb[((size_t)itj[k + 0] << 7) + cp];
            unsigned int u1 = Eb[((size_t)itj[k + 1] << 7) + cp];
            unsigned int u2 = Eb[((size_t)itj[k + 2] << 7) + cp];
            unsigned int u3 = Eb[((size_t)itj[k + 3] << 7) + cp];
            al += lo_bf(u0); ah += hi_bf(u0);
            bl += lo_bf(u1); bh += hi_bf(u1);
            cl += lo_bf(u2); ch += hi_bf(u2);
            dl += lo_bf(u3); dh += hi_bf(u3);
        }
        float2 xv = ((const float2*)(x + (((size_t)(b * NN + n)) << 8)))[cp];
        tile[j][2 * cp + 0] = xv.x + ((al + bl) + (cl + dl));
        tile[j][2 * cp + 1] = xv.y + ((ah + bh) + (ch + dh));
    }
    __syncthreads();

    float sum = 0.f, ss = 0.f;
    #pragma unroll 4
    for (int j = 0; j < 32; ++j) {
        float v = tile[j][tid];
        sum += v; ss += v * v;
    }
    bn1[(size_t)blk * 256 + tid] = sum;
    bn2[(size_t)blk * 256 + tid] = ss;

    for (int i = tid; i < CCH * 32; i += 256) {
        int c2 = i >> 5, j2 = i & 31;
        out[(((size_t)(b * CCH + c2)) << 14) + n0 + j2] = tile[j2][c2];
    }
}

// ---------------- K5: finalize BN stats -> a[c], bb[c] ----------------
__global__ __launch_bounds__(256) void k_stats(const float* __restrict__ bn1,
                                               const float* __restrict__ bn2,
                                               const float* __restrict__ gamma,
                                               const float* __restrict__ beta,
                                               float* __restrict__ ab) {
    __shared__ float r1[256], r2[256];
    int c = blockIdx.x;
    int t = threadIdx.x;
    float s1 = 0.f, s2 = 0.f;
    for (int i = t; i < 2048; i += 256) {
        s1 += bn1[i * 256 + c];
        s2 += bn2[i * 256 + c];
    }
    r1[t] = s1; r2[t] = s2;
    __syncthreads();
    for (int o = 128; o > 0; o >>= 1) {
        if (t < o) { r1[t] += r1[t + o]; r2[t] += r2[t + o]; }
        __syncthreads();
    }
    if (t == 0) {
        float mean = r1[0] * (1.0f / 65536.0f);
        float var  = r2[0] * (1.0f / 65536.0f) - mean * mean;
        float istd = rsqrtf(var + EPSV);
        float a = gamma[c] * istd;
        ab[c] = a;
        ab[CCH + c] = beta[c] - mean * a;
    }
}

// ---------------- K6: in-place normalize + SiLU ----------------
__global__ __launch_bounds__(256) void k_silu(float* __restrict__ out,
                                              const float* __restrict__ ab) {
    int i = blockIdx.x * 256 + threadIdx.x;     // float4 index, 4194304 total
    int c = (i >> 12) & 255;
    float a = ab[c], bb = ab[CCH + c];
    float4 v = ((float4*)out)[i];
    float t0 = a * v.x + bb;
    float t1 = a * v.y + bb;
    float t2 = a * v.z + bb;
    float t3 = a * v.w + bb;
    v.x = t0 / (1.0f + __expf(-t0));
    v.y = t1 / (1.0f + __expf(-t1));
    v.z = t2 / (1.0f + __expf(-t2));
    v.w = t3 / (1.0f + __expf(-t3));
    ((float4*)out)[i] = v;
}

extern "C" void kernel_launch(void* const* d_in, const int* in_sizes, int n_in,
                              void* d_out, int out_size, void* d_ws, size_t ws_size,
                              hipStream_t stream) {
    (void)in_sizes; (void)n_in; (void)out_size; (void)ws_size;
    const float* x       = (const float*)d_in[0];
    const float* coords  = (const float*)d_in[1];
    const float* anchors = (const float*)d_in[2];
    const float* fcw     = (const float*)d_in[3];
    const float* fcb     = (const float*)d_in[4];
    const float* gamma   = (const float*)d_in[5];
    const float* beta    = (const float*)d_in[6];
    float* out = (float*)d_out;

    // bf16-packed x lives in d_out (33.5 MB of 67 MB); dead before k_gather
    // overwrites d_out. ws footprint 16.0 MB (< proven-safe 19.2 MB).
    unsigned int* xh = (unsigned int*)d_out;

    char* ws = (char*)d_ws;
    ushort_t*     ws_idx   = (ushort_t*)    (ws + 0);          // 3,145,728 B
    int*          ws_deg   = (int*)         (ws + 3145728);    //     8,192 B
    int*          ws_offs  = (int*)         (ws + 3153920);    //     8,192 B
    ushort_t*     ws_list  = (ushort_t*)    (ws + 3162112);    // 3,145,728 B
    int*          ws_histT = (int*)         (ws + 6307840);    // 2,097,152 B
    int*          ws_posT  = (int*)         (ws + 8404992);    // 2,097,152 B
    unsigned int* ws_eph   = (unsigned int*)(ws + 10502144);   // 1,048,576 B
    float*        ws_wt    = (float*)       (ws + 11550720);   //   262,144 B
    float*        ws_bn1   = (float*)       (ws + 11812864);   // 2,097,152 B
    float*        ws_bn2   = (float*)       (ws + 13910016);   // 2,097,152 B
    float*        ws_ab    = (float*)       (ws + 16007168);   //     2,048 B

    hipLaunchKernelGGL(k_cvt,     dim3(32768), dim3(256), 0, stream, x, xh);
    hipLaunchKernelGGL(k_wt,      dim3(256),   dim3(256), 0, stream, fcw, ws_wt);
    hipLaunchKernelGGL(k_topk,    dim3(1024),  dim3(128), 0, stream, coords, anchors, ws_idx, ws_histT);
    hipLaunchKernelGGL(k_scan,    dim3(2048),  dim3(64),  0, stream, ws_histT, ws_posT, ws_deg);
    hipLaunchKernelGGL(k_offsets, dim3(1),     dim3(256), 0, stream, ws_deg, ws_offs);
    hipLaunchKernelGGL(k_fill2,   dim3(1024),  dim3(256), 0, stream, (const unsigned int*)ws_idx, ws_posT, ws_offs, ws_list);
    hipLaunchKernelGGL(k_edge2,   dim3(2048),  dim3(256), 0, stream, xh, ws_list, ws_offs, ws_deg, ws_wt, fcb, ws_eph);
    hipLaunchKernelGGL(k_gather,  dim3(2048),  dim3(256), 0, stream, x, (const unsigned int*)ws_idx, ws_eph, out, ws_bn1, ws_bn2);
    hipLaunchKernelGGL(k_stats,   dim3(256),   dim3(256), 0, stream, ws_bn1, ws_bn2, gamma, beta, ws_ab);
    hipLaunchKernelGGL(k_silu,    dim3(16384), dim3(256), 0, stream, out, ws_ab);
}

// Round 10
// 306.642 us; speedup vs baseline: 9.1794x; 1.0097x over previous
//
#include <hip/hip_runtime.h>

#define BB 4
#define NN 16384
#define MM 512
#define CCH 256
#define KNN 24
#define EPSV 1e-5f

typedef unsigned short ushort_t;

__device__ __forceinline__ unsigned int pk_bf16(float a, float b) {
    unsigned int ua = __float_as_uint(a), ub = __float_as_uint(b);
    ua += 0x7FFFu + ((ua >> 16) & 1u);          // RNE to bf16
    ub += 0x7FFFu + ((ub >> 16) & 1u);
    return (ua >> 16) | (ub & 0xFFFF0000u);
}
__device__ __forceinline__ float lo_bf(unsigned int u) { return __uint_as_float(u << 16); }
__device__ __forceinline__ float hi_bf(unsigned int u) { return __uint_as_float(u & 0xFFFF0000u); }

// ---------------- K-1: pack x -> bf16 pairs (uint = 2 channels), lives in d_out ----------------
__global__ __launch_bounds__(256) void k_cvt(const float* __restrict__ x,
                                             unsigned int* __restrict__ xh) {
    int i = blockIdx.x * 256 + threadIdx.x;   // 8,388,608 float2s
    float2 v = ((const float2*)x)[i];
    xh[i] = pk_bf16(v.x, v.y);
}

// ---------------- K0: transpose fc_w (256x256) -> Wt[cin][cout] ----------------
__global__ __launch_bounds__(256) void k_wt(const float* __restrict__ W, float* __restrict__ Wt) {
    int i = blockIdx.x * 256 + threadIdx.x;   // 65536
    int co = i >> 8, ci = i & 255;
    Wt[(ci << 8) + co] = W[i];
}

// ---------------- K1: top-24, packed keys, hard-pinned regs, 4-way pipelined ----------------
// Keys k0..k23 PINNED to v32..v55 (explicit-register constraints kill the AGPR
// shuttle that made rounds 8/9 run at 161 inst/cand with VGPR_Count=24).
// 4 candidates (v56..v59, temps v60..v63) flow through the bubble chain staggered
// one stage apart: every RAW dep is >=6 inst (12 cyc) apart -> no VALU stalls.
// Interleave == sequential insert (cand X's stage j runs after cand X-1's stage j).
#define GA(K) "v_min_u32 v60, v56, " K "\n\tv_max_u32 v56, v56, " K "\n\tv_mov_b32 " K ", v60\n\t"
#define GB(K) "v_min_u32 v61, v57, " K "\n\tv_max_u32 v57, v57, " K "\n\tv_mov_b32 " K ", v61\n\t"
#define GC(K) "v_min_u32 v62, v58, " K "\n\tv_max_u32 v58, v58, " K "\n\tv_mov_b32 " K ", v62\n\t"
#define GD(K) "v_min_u32 v63, v59, " K "\n\tv_max_u32 v59, v59, " K "\n\tv_mov_b32 " K ", v63\n\t"
__global__ __launch_bounds__(128, 2) void k_topk(const float* __restrict__ coords,
                                                 const float* __restrict__ anchors,
                                                 ushort_t* __restrict__ idx_out,
                                                 int* __restrict__ histT) {
    __shared__ float4 alds[MM];     // 8 KB: x,y,z,|a|^2
    __shared__ int    hist[MM];     // 2 KB
    int tid = threadIdx.x;
    int blk = blockIdx.x;           // 1024 blocks: 256 per batch
    int b  = blk >> 8;
    int g  = blk & 255;             // 64-node group id within batch
    int n0 = g << 6;
    int lane = tid & 63;
    int half = lane >> 5;           // 0: anchors 0..255, 1: 256..511
    int n = n0 + ((tid >> 6) << 5) + (lane & 31);

    for (int m = tid; m < MM; m += 128) {
        float x_ = anchors[(b * MM + m) * 3 + 0];
        float y_ = anchors[(b * MM + m) * 3 + 1];
        float z_ = anchors[(b * MM + m) * 3 + 2];
        alds[m] = make_float4(x_, y_, z_, x_ * x_ + y_ * y_ + z_ * z_);
        hist[m] = 0;
    }
    __syncthreads();

    float cx = coords[(b * NN + n) * 3 + 0];
    float cy = coords[(b * NN + n) * 3 + 1];
    float cz = coords[(b * NN + n) * 3 + 2];
    float cn2 = cx * cx + cy * cy + cz * cz;

    unsigned int k0 = 0xFFFFFFFFu, k1 = 0xFFFFFFFFu, k2 = 0xFFFFFFFFu, k3 = 0xFFFFFFFFu,
                 k4 = 0xFFFFFFFFu, k5 = 0xFFFFFFFFu, k6 = 0xFFFFFFFFu, k7 = 0xFFFFFFFFu,
                 k8 = 0xFFFFFFFFu, k9 = 0xFFFFFFFFu, k10 = 0xFFFFFFFFu, k11 = 0xFFFFFFFFu,
                 k12 = 0xFFFFFFFFu, k13 = 0xFFFFFFFFu, k14 = 0xFFFFFFFFu, k15 = 0xFFFFFFFFu,
                 k16 = 0xFFFFFFFFu, k17 = 0xFFFFFFFFu, k18 = 0xFFFFFFFFu, k19 = 0xFFFFFFFFu,
                 k20 = 0xFFFFFFFFu, k21 = 0xFFFFFFFFu, k22 = 0xFFFFFFFFu, k23 = 0xFFFFFFFFu;

    int base = half << 8;
    float4 a0 = alds[base + 0];
    float4 a1 = alds[base + 1];
    float4 a2 = alds[base + 2];
    float4 a3 = alds[base + 3];
    for (int mm = 0; mm < 64; ++mm) {
        int nxt = (4 * mm + 4) & 255;
        float4 p0 = alds[base + nxt + 0];       // prefetch: issued before the asm,
        float4 p1 = alds[base + nxt + 1];       // consumed after -> LDS latency
        float4 p2 = alds[base + nxt + 2];       // hides under the 288-inst chain
        float4 p3 = alds[base + nxt + 3];
        float cd0 = cn2 + a0.w - 2.0f * (cx * a0.x + cy * a0.y + cz * a0.z);
        float cd1 = cn2 + a1.w - 2.0f * (cx * a1.x + cy * a1.y + cz * a1.z);
        float cd2 = cn2 + a2.w - 2.0f * (cx * a2.x + cy * a2.y + cz * a2.z);
        float cd3 = cn2 + a3.w - 2.0f * (cx * a3.x + cy * a3.y + cz * a3.z);
        int id0 = base + 4 * mm;
        unsigned int cA = ((__float_as_uint(cd0) ^ 0x80000000u) & 0xFFFFFE00u) | (unsigned)(id0 + 0);
        unsigned int cB = ((__float_as_uint(cd1) ^ 0x80000000u) & 0xFFFFFE00u) | (unsigned)(id0 + 1);
        unsigned int cC = ((__float_as_uint(cd2) ^ 0x80000000u) & 0xFFFFFE00u) | (unsigned)(id0 + 2);
        unsigned int cD = ((__float_as_uint(cd3) ^ 0x80000000u) & 0xFFFFFE00u) | (unsigned)(id0 + 3);
        asm volatile(
            GA("v32")
            GA("v33") GB("v32")
            GA("v34") GB("v33") GC("v32")
            GA("v35") GB("v34") GC("v33") GD("v32")
            GA("v36") GB("v35") GC("v34") GD("v33")
            GA("v37") GB("v36") GC("v35") GD("v34")
            GA("v38") GB("v37") GC("v36") GD("v35")
            GA("v39") GB("v38") GC("v37") GD("v36")
            GA("v40") GB("v39") GC("v38") GD("v37")
            GA("v41") GB("v40") GC("v39") GD("v38")
            GA("v42") GB("v41") GC("v40") GD("v39")
            GA("v43") GB("v42") GC("v41") GD("v40")
            GA("v44") GB("v43") GC("v42") GD("v41")
            GA("v45") GB("v44") GC("v43") GD("v42")
            GA("v46") GB("v45") GC("v44") GD("v43")
            GA("v47") GB("v46") GC("v45") GD("v44")
            GA("v48") GB("v47") GC("v46") GD("v45")
            GA("v49") GB("v48") GC("v47") GD("v46")
            GA("v50") GB("v49") GC("v48") GD("v47")
            GA("v51") GB("v50") GC("v49") GD("v48")
            GA("v52") GB("v51") GC("v50") GD("v49")
            GA("v53") GB("v52") GC("v51") GD("v50")
            GA("v54") GB("v53") GC("v52") GD("v51")
            GA("v55") GB("v54") GC("v53") GD("v52")
                      GB("v55") GC("v54") GD("v53")
                                GC("v55") GD("v54")
                                          GD("v55")
            : "+{v32}"(k0),  "+{v33}"(k1),  "+{v34}"(k2),  "+{v35}"(k3),
              "+{v36}"(k4),  "+{v37}"(k5),  "+{v38}"(k6),  "+{v39}"(k7),
              "+{v40}"(k8),  "+{v41}"(k9),  "+{v42}"(k10), "+{v43}"(k11),
              "+{v44}"(k12), "+{v45}"(k13), "+{v46}"(k14), "+{v47}"(k15),
              "+{v48}"(k16), "+{v49}"(k17), "+{v50}"(k18), "+{v51}"(k19),
              "+{v52}"(k20), "+{v53}"(k21), "+{v54}"(k22), "+{v55}"(k23),
              "+{v56}"(cA), "+{v57}"(cB), "+{v58}"(cC), "+{v59}"(cD)
            :
            : "v60", "v61", "v62", "v63");
        a0 = p0; a1 = p1; a2 = p2; a3 = p3;
    }

    unsigned int kk[24] = {k0, k1, k2, k3, k4, k5, k6, k7, k8, k9, k10, k11,
                           k12, k13, k14, k15, k16, k17, k18, k19, k20, k21, k22, k23};

    // cross-lane merge: global top-24 = multiset { min(A[i], B[23-i]) }.
    int Mi[12];
    #pragma unroll
    for (int j = 0; j < 12; ++j) {
        unsigned int sA = __shfl_xor(kk[23 - j], 32);
        unsigned int sB = __shfl_xor(kk[12 + j], 32);
        unsigned int mi = (half == 0) ? min(kk[j], sA) : min(sB, kk[11 - j]);
        Mi[j] = (int)(mi & 511u);
    }

    #pragma unroll
    for (int j = 0; j < 12; ++j) atomicAdd(&hist[Mi[j]], 1);

    unsigned int* ob = (unsigned int*)(idx_out + (size_t)(b * NN + n) * KNN + half * 12);
    ob[0] = (unsigned)(Mi[0] | (Mi[1] << 16));
    ob[1] = (unsigned)(Mi[2] | (Mi[3] << 16));
    ob[2] = (unsigned)(Mi[4] | (Mi[5] << 16));
    ob[3] = (unsigned)(Mi[6] | (Mi[7] << 16));
    ob[4] = (unsigned)(Mi[8] | (Mi[9] << 16));
    ob[5] = (unsigned)(Mi[10] | (Mi[11] << 16));

    __syncthreads();
    // counting-sort input: histT[((b*512)+m)*256 + g]
    for (int m = tid; m < MM; m += 128)
        histT[((((b << 9) + m)) << 8) + g] = hist[m];
}

// ---------------- K1b: per-edge scan over the 256 groups -> posT, deg ----------------
__global__ __launch_bounds__(64) void k_scan(const int* __restrict__ histT,
                                             int* __restrict__ posT,
                                             int* __restrict__ deg) {
    int e = blockIdx.x;             // 2048 = (b<<9)+m
    int t = threadIdx.x;
    int4 v = ((const int4*)(histT + (e << 8)))[t];   // 4 consecutive g per lane
    int s = v.x + v.y + v.z + v.w;
    int inc = s;
    #pragma unroll
    for (int off = 1; off < 64; off <<= 1) {
        int u = __shfl_up(inc, off);
        if (t >= off) inc += u;
    }
    int excl = inc - s;
    int4 o;
    o.x = excl; o.y = excl + v.x; o.z = o.y + v.y; o.w = o.z + v.z;
    ((int4*)(posT + (e << 8)))[t] = o;
    if (t == 63) deg[e] = inc;
}

// ---------------- K2a: exclusive prefix sum of deg (2048) -> offs ----------------
__global__ __launch_bounds__(256) void k_offsets(const int* __restrict__ deg,
                                                 int* __restrict__ offs) {
    __shared__ int part[256];
    int t = threadIdx.x;
    int v[8];
    int s = 0;
    #pragma unroll
    for (int j = 0; j < 8; ++j) { v[j] = deg[t * 8 + j]; s += v[j]; }
    part[t] = s;
    __syncthreads();
    for (int off = 1; off < 256; off <<= 1) {
        int val = (t >= off) ? part[t - off] : 0;
        __syncthreads();
        part[t] += val;
        __syncthreads();
    }
    int excl = part[t] - s;
    #pragma unroll
    for (int j = 0; j < 8; ++j) { offs[t * 8 + j] = excl; excl += v[j]; }
}

// ---------------- K2b: counting-sort scatter (LDS cursors, no global atomics) ----------------
__global__ __launch_bounds__(256) void k_fill2(const unsigned int* __restrict__ idxu,
                                               const int* __restrict__ posT,
                                               const int* __restrict__ offs,
                                               ushort_t* __restrict__ list) {
    __shared__ int pos[MM];
    __shared__ unsigned int ebuf[768];      // 64 nodes x 12 packed uints
    int tid = threadIdx.x;
    int blk = blockIdx.x;                   // 1024 = (b<<8)+g
    int b = blk >> 8, g = blk & 255;
    int n0 = g << 6;

    for (int m = tid; m < MM; m += 256) {
        int e = (b << 9) + m;
        pos[m] = offs[e] + posT[(e << 8) + g];
    }
    for (int i = tid; i < 768; i += 256)
        ebuf[i] = idxu[(size_t)(b * NN + n0) * 12 + i];
    __syncthreads();

    for (int i = tid; i < 768; i += 256) {
        unsigned int u = ebuf[i];
        int node = n0 + (i / 12);
        int p0 = atomicAdd(&pos[u & 0xFFFFu], 1);
        list[p0] = (ushort_t)node;
        int p1 = atomicAdd(&pos[u >> 16], 1);
        list[p1] = (ushort_t)node;
    }
}

// ---------------- K3: E' = ((gather(xh)*inv_e)@W^T + b*(deg>0)) / 24, bf16 out ----------------
__global__ __launch_bounds__(256) void k_edge2(const unsigned int* __restrict__ xh,
                                               const ushort_t* __restrict__ list,
                                               const int* __restrict__ offs,
                                               const int* __restrict__ deg,
                                               const float* __restrict__ Wt,
                                               const float* __restrict__ fcb,
                                               unsigned int* __restrict__ Eph) {
    __shared__ ushort_t nl[256];
    __shared__ float part[2][128][2];
    __shared__ float srow[CCH];
    __shared__ float rrow[CCH];
    int tid = threadIdx.x;
    int blk = blockIdx.x;               // b*512 + m
    int b = blk >> 9;
    int d = deg[blk];
    int o = offs[blk];
    int cp = tid & 127, rs = tid >> 7;  // channel pair, row parity
    const unsigned int* xb = xh + ((size_t)b << 21);   // b * NN * 128

    float l0 = 0.f, l1 = 0.f, l2 = 0.f, l3 = 0.f;
    float h0 = 0.f, h1 = 0.f, h2 = 0.f, h3 = 0.f;
    for (int base2 = 0; base2 < d; base2 += 256) {
        int cnt = min(256, d - base2);
        if (tid < cnt) nl[tid] = list[(size_t)o + base2 + tid];
        __syncthreads();
        int i = 0;
        for (; i + 7 < cnt; i += 8) {
            unsigned int u0 = xb[((size_t)nl[i + 0 + rs] << 7) + cp];
            unsigned int u1 = xb[((size_t)nl[i + 2 + rs] << 7) + cp];
            unsigned int u2 = xb[((size_t)nl[i + 4 + rs] << 7) + cp];
            unsigned int u3 = xb[((size_t)nl[i + 6 + rs] << 7) + cp];
            l0 += lo_bf(u0); h0 += hi_bf(u0);
            l1 += lo_bf(u1); h1 += hi_bf(u1);
            l2 += lo_bf(u2); h2 += hi_bf(u2);
            l3 += lo_bf(u3); h3 += hi_bf(u3);
        }
        for (; i + 1 < cnt; i += 2) {
            unsigned int u = xb[((size_t)nl[i + rs] << 7) + cp];
            l0 += lo_bf(u); h0 += hi_bf(u);
        }
        if (i < cnt && rs == 0) {
            unsigned int u = xb[((size_t)nl[i] << 7) + cp];
            l0 += lo_bf(u); h0 += hi_bf(u);
        }
        __syncthreads();
    }
    part[rs][cp][0] = (l0 + l1) + (l2 + l3);
    part[rs][cp][1] = (h0 + h1) + (h2 + h3);
    __syncthreads();
    float inv = (d > 0) ? (1.0f / (float)d) : 0.0f;
    srow[tid] = (part[0][tid >> 1][tid & 1] + part[1][tid >> 1][tid & 1]) * inv;
    __syncthreads();

    float c0 = (d > 0) ? fcb[tid] : 0.0f;
    float c1 = 0.f, c2 = 0.f, c3 = 0.f;
    #pragma unroll 4
    for (int ci = 0; ci < CCH; ci += 4) {
        c0 = fmaf(srow[ci + 0], Wt[((ci + 0) << 8) + tid], c0);
        c1 = fmaf(srow[ci + 1], Wt[((ci + 1) << 8) + tid], c1);
        c2 = fmaf(srow[ci + 2], Wt[((ci + 2) << 8) + tid], c2);
        c3 = fmaf(srow[ci + 3], Wt[((ci + 3) << 8) + tid], c3);
    }
    rrow[tid] = ((c0 + c1) + (c2 + c3)) * (1.0f / 24.0f);
    __syncthreads();
    if (tid < 128) Eph[(size_t)blk * 128 + tid] = pk_bf16(rrow[2 * tid], rrow[2 * tid + 1]);
}

// ---------------- K4: out = H@E' + x, transposed write + BN partials ----------------
__global__ __launch_bounds__(256) void k_gather(const float* __restrict__ x,
                                                const unsigned int* __restrict__ idxu,
                                                const unsigned int* __restrict__ Eph,
                                                float* __restrict__ out,
                                                float* __restrict__ bn1,
                                                float* __restrict__ bn2) {
    __shared__ int   it[32 * KNN];          // 768 ints
    __shared__ float tile[32][CCH + 1];     // 32 x 257 = 32.9 KB
    int tid = threadIdx.x;
    int blk = blockIdx.x;                   // 2048: b * 512 node-chunks
    int b = blk >> 9;
    int n0 = (blk & 511) << 5;              // 32 nodes
    int cp = tid & 127, rs = tid >> 7;

    for (int i = tid; i < 32 * 12; i += 256) {           // 384 packed uints
        unsigned int u = idxu[(size_t)(b * NN + n0) * 12 + i];
        it[2 * i] = u & 0xFFFF;
        it[2 * i + 1] = u >> 16;
    }
    __syncthreads();

    const unsigned int* Eb = Eph + ((size_t)(b * MM) << 7);
    for (int j2 = 0; j2 < 16; ++j2) {
        int j = 2 * j2 + rs;
        int n = n0 + j;
        const int* itj = &it[j * KNN];
        float al = 0.f, ah = 0.f, bl = 0.f, bh = 0.f;
        float cl = 0.f, ch = 0.f, dl = 0.f, dh = 0.f;
        #pragma unroll
        for (int k = 0; k < KNN; k += 4) {
            unsigned int u0 = Eb[((size_t)itj[k + 0] << 7) + cp];
            unsigned int u1 = Eb[((size_t)itj[k + 1] << 7) + cp];
            unsigned int u2 = Eb[((size_t)itj[k + 2] << 7) + cp];
            unsigned int u3 = Eb[((size_t)itj[k + 3] << 7) + cp];
            al += lo_bf(u0); ah += hi_bf(u0);
            bl += lo_bf(u1); bh += hi_bf(u1);
            cl += lo_bf(u2); ch += hi_bf(u2);
            dl += lo_bf(u3); dh += hi_bf(u3);
        }
        float2 xv = ((const float2*)(x + (((size_t)(b * NN + n)) << 8)))[cp];
        tile[j][2 * cp + 0] = xv.x + ((al + bl) + (cl + dl));
        tile[j][2 * cp + 1] = xv.y + ((ah + bh) + (ch + dh));
    }
    __syncthreads();

    float sum = 0.f, ss = 0.f;
    #pragma unroll 4
    for (int j = 0; j < 32; ++j) {
        float v = tile[j][tid];
        sum += v; ss += v * v;
    }
    bn1[(size_t)blk * 256 + tid] = sum;
    bn2[(size_t)blk * 256 + tid] = ss;

    for (int i = tid; i < CCH * 32; i += 256) {
        int c2 = i >> 5, j2 = i & 31;
        out[(((size_t)(b * CCH + c2)) << 14) + n0 + j2] = tile[j2][c2];
    }
}

// ---------------- K5: finalize BN stats -> a[c], bb[c] ----------------
__global__ __launch_bounds__(256) void k_stats(const float* __restrict__ bn1,
                                               const float* __restrict__ bn2,
                                               const float* __restrict__ gamma,
                                               const float* __restrict__ beta,
                                               float* __restrict__ ab) {
    __shared__ float r1[256], r2[256];
    int c = blockIdx.x;
    int t = threadIdx.x;
    float s1 = 0.f, s2 = 0.f;
    for (int i = t; i < 2048; i += 256) {
        s1 += bn1[i * 256 + c];
        s2 += bn2[i * 256 + c];
    }
    r1[t] = s1; r2[t] = s2;
    __syncthreads();
    for (int o = 128; o > 0; o >>= 1) {
        if (t < o) { r1[t] += r1[t + o]; r2[t] += r2[t + o]; }
        __syncthreads();
    }
    if (t == 0) {
        float mean = r1[0] * (1.0f / 65536.0f);
        float var  = r2[0] * (1.0f / 65536.0f) - mean * mean;
        float istd = rsqrtf(var + EPSV);
        float a = gamma[c] * istd;
        ab[c] = a;
        ab[CCH + c] = beta[c] - mean * a;
    }
}

// ---------------- K6: in-place normalize + SiLU ----------------
__global__ __launch_bounds__(256) void k_silu(float* __restrict__ out,
                                              const float* __restrict__ ab) {
    int i = blockIdx.x * 256 + threadIdx.x;     // float4 index, 4194304 total
    int c = (i >> 12) & 255;
    float a = ab[c], bb = ab[CCH + c];
    float4 v = ((float4*)out)[i];
    float t0 = a * v.x + bb;
    float t1 = a * v.y + bb;
    float t2 = a * v.z + bb;
    float t3 = a * v.w + bb;
    v.x = t0 / (1.0f + __expf(-t0));
    v.y = t1 / (1.0f + __expf(-t1));
    v.z = t2 / (1.0f + __expf(-t2));
    v.w = t3 / (1.0f + __expf(-t3));
    ((float4*)out)[i] = v;
}

extern "C" void kernel_launch(void* const* d_in, const int* in_sizes, int n_in,
                              void* d_out, int out_size, void* d_ws, size_t ws_size,
                              hipStream_t stream) {
    (void)in_sizes; (void)n_in; (void)out_size; (void)ws_size;
    const float* x       = (const float*)d_in[0];
    const float* coords  = (const float*)d_in[1];
    const float* anchors = (const float*)d_in[2];
    const float* fcw     = (const float*)d_in[3];
    const float* fcb     = (const float*)d_in[4];
    const float* gamma   = (const float*)d_in[5];
    const float* beta    = (const float*)d_in[6];
    float* out = (float*)d_out;

    // bf16-packed x lives in d_out (33.5 MB of 67 MB); dead before k_gather
    // overwrites d_out. ws footprint 16.0 MB (< proven-safe 19.2 MB).
    unsigned int* xh = (unsigned int*)d_out;

    char* ws = (char*)d_ws;
    ushort_t*     ws_idx   = (ushort_t*)    (ws + 0);          // 3,145,728 B
    int*          ws_deg   = (int*)         (ws + 3145728);    //     8,192 B
    int*          ws_offs  = (int*)         (ws + 3153920);    //     8,192 B
    ushort_t*     ws_list  = (ushort_t*)    (ws + 3162112);    // 3,145,728 B
    int*          ws_histT = (int*)         (ws + 6307840);    // 2,097,152 B
    int*          ws_posT  = (int*)         (ws + 8404992);    // 2,097,152 B
    unsigned int* ws_eph   = (unsigned int*)(ws + 10502144);   // 1,048,576 B
    float*        ws_wt    = (float*)       (ws + 11550720);   //   262,144 B
    float*        ws_bn1   = (float*)       (ws + 11812864);   // 2,097,152 B
    float*        ws_bn2   = (float*)       (ws + 13910016);   // 2,097,152 B
    float*        ws_ab    = (float*)       (ws + 16007168);   //     2,048 B

    hipLaunchKernelGGL(k_cvt,     dim3(32768), dim3(256), 0, stream, x, xh);
    hipLaunchKernelGGL(k_wt,      dim3(256),   dim3(256), 0, stream, fcw, ws_wt);
    hipLaunchKernelGGL(k_topk,    dim3(1024),  dim3(128), 0, stream, coords, anchors, ws_idx, ws_histT);
    hipLaunchKernelGGL(k_scan,    dim3(2048),  dim3(64),  0, stream, ws_histT, ws_posT, ws_deg);
    hipLaunchKernelGGL(k_offsets, dim3(1),     dim3(256), 0, stream, ws_deg, ws_offs);
    hipLaunchKernelGGL(k_fill2,   dim3(1024),  dim3(256), 0, stream, (const unsigned int*)ws_idx, ws_posT, ws_offs, ws_list);
    hipLaunchKernelGGL(k_edge2,   dim3(2048),  dim3(256), 0, stream, xh, ws_list, ws_offs, ws_deg, ws_wt, fcb, ws_eph);
    hipLaunchKernelGGL(k_gather,  dim3(2048),  dim3(256), 0, stream, x, (const unsigned int*)ws_idx, ws_eph, out, ws_bn1, ws_bn2);
    hipLaunchKernelGGL(k_stats,   dim3(256),   dim3(256), 0, stream, ws_bn1, ws_bn2, gamma, beta, ws_ab);
    hipLaunchKernelGGL(k_silu,    dim3(16384), dim3(256), 0, stream, out, ws_ab);
}

// Round 11
// 293.187 us; speedup vs baseline: 9.6006x; 1.0459x over previous
//
#include <hip/hip_runtime.h>

#define BB 4
#define NN 16384
#define MM 512
#define CCH 256
#define KNN 24
#define EPSV 1e-5f

typedef unsigned short ushort_t;

__device__ __forceinline__ unsigned int pk_bf16(float a, float b) {
    unsigned int ua = __float_as_uint(a), ub = __float_as_uint(b);
    ua += 0x7FFFu + ((ua >> 16) & 1u);          // RNE to bf16
    ub += 0x7FFFu + ((ub >> 16) & 1u);
    return (ua >> 16) | (ub & 0xFFFF0000u);
}
__device__ __forceinline__ float lo_bf(unsigned int u) { return __uint_as_float(u << 16); }
__device__ __forceinline__ float hi_bf(unsigned int u) { return __uint_as_float(u & 0xFFFF0000u); }

// ---------------- K-1: pack x -> bf16 pairs (uint = 2 channels), lives in d_out ----------------
__global__ __launch_bounds__(256) void k_cvt(const float* __restrict__ x,
                                             unsigned int* __restrict__ xh) {
    int i = blockIdx.x * 256 + threadIdx.x;   // 8,388,608 float2s
    float2 v = ((const float2*)x)[i];
    xh[i] = pk_bf16(v.x, v.y);
}

// ---------------- K0: transpose fc_w (256x256) -> Wt[cin][cout] ----------------
__global__ __launch_bounds__(256) void k_wt(const float* __restrict__ W, float* __restrict__ Wt) {
    int i = blockIdx.x * 256 + threadIdx.x;   // 65536
    int co = i >> 8, ci = i & 255;
    Wt[(ci << 8) + co] = W[i];
}

// ---------------- K1: top-24, packed keys, pinned v64-v95, 2-op bubble ----------------
// Keys k0..k23 pinned to v64..v87; compiler keeps v0..v63 (no spill -- round 10
// pinned v32..v63 and squeezed the compiler's 8 live float4s into 32 regs -> scratch).
// Bubble step is 2 ops via alternating carries: max c_out,c_in,kj ; min kj,c_in,kj
// (both read OLD kj/c_in -> no mov). Carry ping-pongs per candidate: A v88/v89,
// B v90/v91, C v92/v93, D v94/v95; parity = stage index. 4 candidates staggered
// one stage apart: steady-state RAW distance = 8 inst (16 cyc) >> 4-cyc latency.
#define AE(K) "v_max_u32 v89, v88, " K "\n\tv_min_u32 " K ", v88, " K "\n\t"
#define AO(K) "v_max_u32 v88, v89, " K "\n\tv_min_u32 " K ", v89, " K "\n\t"
#define BE(K) "v_max_u32 v91, v90, " K "\n\tv_min_u32 " K ", v90, " K "\n\t"
#define BO(K) "v_max_u32 v90, v91, " K "\n\tv_min_u32 " K ", v91, " K "\n\t"
#define CE(K) "v_max_u32 v93, v92, " K "\n\tv_min_u32 " K ", v92, " K "\n\t"
#define CO(K) "v_max_u32 v92, v93, " K "\n\tv_min_u32 " K ", v93, " K "\n\t"
#define DE(K) "v_max_u32 v95, v94, " K "\n\tv_min_u32 " K ", v94, " K "\n\t"
#define DO_(K) "v_max_u32 v94, v95, " K "\n\tv_min_u32 " K ", v95, " K "\n\t"
__global__ __launch_bounds__(128, 2) void k_topk(const float* __restrict__ coords,
                                                 const float* __restrict__ anchors,
                                                 ushort_t* __restrict__ idx_out,
                                                 int* __restrict__ histT) {
    __shared__ float4 alds[MM];     // 8 KB: x,y,z,|a|^2
    __shared__ int    hist[MM];     // 2 KB
    int tid = threadIdx.x;
    int blk = blockIdx.x;           // 1024 blocks: 256 per batch
    int b  = blk >> 8;
    int g  = blk & 255;             // 64-node group id within batch
    int n0 = g << 6;
    int lane = tid & 63;
    int half = lane >> 5;           // 0: anchors 0..255, 1: 256..511
    int n = n0 + ((tid >> 6) << 5) + (lane & 31);

    for (int m = tid; m < MM; m += 128) {
        float x_ = anchors[(b * MM + m) * 3 + 0];
        float y_ = anchors[(b * MM + m) * 3 + 1];
        float z_ = anchors[(b * MM + m) * 3 + 2];
        alds[m] = make_float4(x_, y_, z_, x_ * x_ + y_ * y_ + z_ * z_);
        hist[m] = 0;
    }
    __syncthreads();

    float cx = coords[(b * NN + n) * 3 + 0];
    float cy = coords[(b * NN + n) * 3 + 1];
    float cz = coords[(b * NN + n) * 3 + 2];
    float cn2 = cx * cx + cy * cy + cz * cz;

    unsigned int k0 = 0xFFFFFFFFu, k1 = 0xFFFFFFFFu, k2 = 0xFFFFFFFFu, k3 = 0xFFFFFFFFu,
                 k4 = 0xFFFFFFFFu, k5 = 0xFFFFFFFFu, k6 = 0xFFFFFFFFu, k7 = 0xFFFFFFFFu,
                 k8 = 0xFFFFFFFFu, k9 = 0xFFFFFFFFu, k10 = 0xFFFFFFFFu, k11 = 0xFFFFFFFFu,
                 k12 = 0xFFFFFFFFu, k13 = 0xFFFFFFFFu, k14 = 0xFFFFFFFFu, k15 = 0xFFFFFFFFu,
                 k16 = 0xFFFFFFFFu, k17 = 0xFFFFFFFFu, k18 = 0xFFFFFFFFu, k19 = 0xFFFFFFFFu,
                 k20 = 0xFFFFFFFFu, k21 = 0xFFFFFFFFu, k22 = 0xFFFFFFFFu, k23 = 0xFFFFFFFFu;

    int base = half << 8;
    float4 a0 = alds[base + 0];
    float4 a1 = alds[base + 1];
    float4 a2 = alds[base + 2];
    float4 a3 = alds[base + 3];
    for (int mm = 0; mm < 64; ++mm) {
        int nxt = (4 * mm + 4) & 255;
        float4 p0 = alds[base + nxt + 0];       // prefetch: issued before the asm,
        float4 p1 = alds[base + nxt + 1];       // consumed after -> LDS latency
        float4 p2 = alds[base + nxt + 2];       // hides under the 192-inst chain
        float4 p3 = alds[base + nxt + 3];
        float cd0 = cn2 + a0.w - 2.0f * (cx * a0.x + cy * a0.y + cz * a0.z);
        float cd1 = cn2 + a1.w - 2.0f * (cx * a1.x + cy * a1.y + cz * a1.z);
        float cd2 = cn2 + a2.w - 2.0f * (cx * a2.x + cy * a2.y + cz * a2.z);
        float cd3 = cn2 + a3.w - 2.0f * (cx * a3.x + cy * a3.y + cz * a3.z);
        int id0 = base + 4 * mm;
        unsigned int cA = ((__float_as_uint(cd0) ^ 0x80000000u) & 0xFFFFFE00u) | (unsigned)(id0 + 0);
        unsigned int cB = ((__float_as_uint(cd1) ^ 0x80000000u) & 0xFFFFFE00u) | (unsigned)(id0 + 1);
        unsigned int cC = ((__float_as_uint(cd2) ^ 0x80000000u) & 0xFFFFFE00u) | (unsigned)(id0 + 2);
        unsigned int cD = ((__float_as_uint(cd3) ^ 0x80000000u) & 0xFFFFFE00u) | (unsigned)(id0 + 3);
        asm volatile(
            AE("v64")
            AO("v65") BE("v64")
            AE("v66") BO("v65") CE("v64")
            AO("v67") BE("v66") CO("v65") DE("v64")
            AE("v68") BO("v67") CE("v66") DO_("v65")
            AO("v69") BE("v68") CO("v67") DE("v66")
            AE("v70") BO("v69") CE("v68") DO_("v67")
            AO("v71") BE("v70") CO("v69") DE("v68")
            AE("v72") BO("v71") CE("v70") DO_("v69")
            AO("v73") BE("v72") CO("v71") DE("v70")
            AE("v74") BO("v73") CE("v72") DO_("v71")
            AO("v75") BE("v74") CO("v73") DE("v72")
            AE("v76") BO("v75") CE("v74") DO_("v73")
            AO("v77") BE("v76") CO("v75") DE("v74")
            AE("v78") BO("v77") CE("v76") DO_("v75")
            AO("v79") BE("v78") CO("v77") DE("v76")
            AE("v80") BO("v79") CE("v78") DO_("v77")
            AO("v81") BE("v80") CO("v79") DE("v78")
            AE("v82") BO("v81") CE("v80") DO_("v79")
            AO("v83") BE("v82") CO("v81") DE("v80")
            AE("v84") BO("v83") CE("v82") DO_("v81")
            AO("v85") BE("v84") CO("v83") DE("v82")
            AE("v86") BO("v85") CE("v84") DO_("v83")
            AO("v87") BE("v86") CO("v85") DE("v84")
                      BO("v87") CE("v86") DO_("v85")
                                CO("v87") DE("v86")
                                          DO_("v87")
            : "+{v64}"(k0),  "+{v65}"(k1),  "+{v66}"(k2),  "+{v67}"(k3),
              "+{v68}"(k4),  "+{v69}"(k5),  "+{v70}"(k6),  "+{v71}"(k7),
              "+{v72}"(k8),  "+{v73}"(k9),  "+{v74}"(k10), "+{v75}"(k11),
              "+{v76}"(k12), "+{v77}"(k13), "+{v78}"(k14), "+{v79}"(k15),
              "+{v80}"(k16), "+{v81}"(k17), "+{v82}"(k18), "+{v83}"(k19),
              "+{v84}"(k20), "+{v85}"(k21), "+{v86}"(k22), "+{v87}"(k23),
              "+{v88}"(cA), "+{v90}"(cB), "+{v92}"(cC), "+{v94}"(cD)
            :
            : "v89", "v91", "v93", "v95");
        a0 = p0; a1 = p1; a2 = p2; a3 = p3;
    }

    unsigned int kk[24] = {k0, k1, k2, k3, k4, k5, k6, k7, k8, k9, k10, k11,
                           k12, k13, k14, k15, k16, k17, k18, k19, k20, k21, k22, k23};

    // cross-lane merge: global top-24 = multiset { min(A[i], B[23-i]) }.
    int Mi[12];
    #pragma unroll
    for (int j = 0; j < 12; ++j) {
        unsigned int sA = __shfl_xor(kk[23 - j], 32);
        unsigned int sB = __shfl_xor(kk[12 + j], 32);
        unsigned int mi = (half == 0) ? min(kk[j], sA) : min(sB, kk[11 - j]);
        Mi[j] = (int)(mi & 511u);
    }

    #pragma unroll
    for (int j = 0; j < 12; ++j) atomicAdd(&hist[Mi[j]], 1);

    unsigned int* ob = (unsigned int*)(idx_out + (size_t)(b * NN + n) * KNN + half * 12);
    ob[0] = (unsigned)(Mi[0] | (Mi[1] << 16));
    ob[1] = (unsigned)(Mi[2] | (Mi[3] << 16));
    ob[2] = (unsigned)(Mi[4] | (Mi[5] << 16));
    ob[3] = (unsigned)(Mi[6] | (Mi[7] << 16));
    ob[4] = (unsigned)(Mi[8] | (Mi[9] << 16));
    ob[5] = (unsigned)(Mi[10] | (Mi[11] << 16));

    __syncthreads();
    // counting-sort input: histT[((b*512)+m)*256 + g]
    for (int m = tid; m < MM; m += 128)
        histT[((((b << 9) + m)) << 8) + g] = hist[m];
}

// ---------------- K1b: per-edge scan over the 256 groups -> posT, deg ----------------
__global__ __launch_bounds__(64) void k_scan(const int* __restrict__ histT,
                                             int* __restrict__ posT,
                                             int* __restrict__ deg) {
    int e = blockIdx.x;             // 2048 = (b<<9)+m
    int t = threadIdx.x;
    int4 v = ((const int4*)(histT + (e << 8)))[t];   // 4 consecutive g per lane
    int s = v.x + v.y + v.z + v.w;
    int inc = s;
    #pragma unroll
    for (int off = 1; off < 64; off <<= 1) {
        int u = __shfl_up(inc, off);
        if (t >= off) inc += u;
    }
    int excl = inc - s;
    int4 o;
    o.x = excl; o.y = excl + v.x; o.z = o.y + v.y; o.w = o.z + v.z;
    ((int4*)(posT + (e << 8)))[t] = o;
    if (t == 63) deg[e] = inc;
}

// ---------------- K2a: exclusive prefix sum of deg (2048) -> offs ----------------
__global__ __launch_bounds__(256) void k_offsets(const int* __restrict__ deg,
                                                 int* __restrict__ offs) {
    __shared__ int part[256];
    int t = threadIdx.x;
    int v[8];
    int s = 0;
    #pragma unroll
    for (int j = 0; j < 8; ++j) { v[j] = deg[t * 8 + j]; s += v[j]; }
    part[t] = s;
    __syncthreads();
    for (int off = 1; off < 256; off <<= 1) {
        int val = (t >= off) ? part[t - off] : 0;
        __syncthreads();
        part[t] += val;
        __syncthreads();
    }
    int excl = part[t] - s;
    #pragma unroll
    for (int j = 0; j < 8; ++j) { offs[t * 8 + j] = excl; excl += v[j]; }
}

// ---------------- K2b: counting-sort scatter (LDS cursors, no global atomics) ----------------
__global__ __launch_bounds__(256) void k_fill2(const unsigned int* __restrict__ idxu,
                                               const int* __restrict__ posT,
                                               const int* __restrict__ offs,
                                               ushort_t* __restrict__ list) {
    __shared__ int pos[MM];
    __shared__ unsigned int ebuf[768];      // 64 nodes x 12 packed uints
    int tid = threadIdx.x;
    int blk = blockIdx.x;                   // 1024 = (b<<8)+g
    int b = blk >> 8, g = blk & 255;
    int n0 = g << 6;

    for (int m = tid; m < MM; m += 256) {
        int e = (b << 9) + m;
        pos[m] = offs[e] + posT[(e << 8) + g];
    }
    for (int i = tid; i < 768; i += 256)
        ebuf[i] = idxu[(size_t)(b * NN + n0) * 12 + i];
    __syncthreads();

    for (int i = tid; i < 768; i += 256) {
        unsigned int u = ebuf[i];
        int node = n0 + (i / 12);
        int p0 = atomicAdd(&pos[u & 0xFFFFu], 1);
        list[p0] = (ushort_t)node;
        int p1 = atomicAdd(&pos[u >> 16], 1);
        list[p1] = (ushort_t)node;
    }
}

// ---------------- K3: E' = ((gather(xh)*inv_e)@W^T + b*(deg>0)) / 24, bf16 out ----------------
__global__ __launch_bounds__(256) void k_edge2(const unsigned int* __restrict__ xh,
                                               const ushort_t* __restrict__ list,
                                               const int* __restrict__ offs,
                                               const int* __restrict__ deg,
                                               const float* __restrict__ Wt,
                                               const float* __restrict__ fcb,
                                               unsigned int* __restrict__ Eph) {
    __shared__ ushort_t nl[256];
    __shared__ float part[2][128][2];
    __shared__ float srow[CCH];
    __shared__ float rrow[CCH];
    int tid = threadIdx.x;
    int blk = blockIdx.x;               // b*512 + m
    int b = blk >> 9;
    int d = deg[blk];
    int o = offs[blk];
    int cp = tid & 127, rs = tid >> 7;  // channel pair, row parity
    const unsigned int* xb = xh + ((size_t)b << 21);   // b * NN * 128

    float l0 = 0.f, l1 = 0.f, l2 = 0.f, l3 = 0.f;
    float h0 = 0.f, h1 = 0.f, h2 = 0.f, h3 = 0.f;
    for (int base2 = 0; base2 < d; base2 += 256) {
        int cnt = min(256, d - base2);
        if (tid < cnt) nl[tid] = list[(size_t)o + base2 + tid];
        __syncthreads();
        int i = 0;
        for (; i + 7 < cnt; i += 8) {
            unsigned int u0 = xb[((size_t)nl[i + 0 + rs] << 7) + cp];
            unsigned int u1 = xb[((size_t)nl[i + 2 + rs] << 7) + cp];
            unsigned int u2 = xb[((size_t)nl[i + 4 + rs] << 7) + cp];
            unsigned int u3 = xb[((size_t)nl[i + 6 + rs] << 7) + cp];
            l0 += lo_bf(u0); h0 += hi_bf(u0);
            l1 += lo_bf(u1); h1 += hi_bf(u1);
            l2 += lo_bf(u2); h2 += hi_bf(u2);
            l3 += lo_bf(u3); h3 += hi_bf(u3);
        }
        for (; i + 1 < cnt; i += 2) {
            unsigned int u = xb[((size_t)nl[i + rs] << 7) + cp];
            l0 += lo_bf(u); h0 += hi_bf(u);
        }
        if (i < cnt && rs == 0) {
            unsigned int u = xb[((size_t)nl[i] << 7) + cp];
            l0 += lo_bf(u); h0 += hi_bf(u);
        }
        __syncthreads();
    }
    part[rs][cp][0] = (l0 + l1) + (l2 + l3);
    part[rs][cp][1] = (h0 + h1) + (h2 + h3);
    __syncthreads();
    float inv = (d > 0) ? (1.0f / (float)d) : 0.0f;
    srow[tid] = (part[0][tid >> 1][tid & 1] + part[1][tid >> 1][tid & 1]) * inv;
    __syncthreads();

    float c0 = (d > 0) ? fcb[tid] : 0.0f;
    float c1 = 0.f, c2 = 0.f, c3 = 0.f;
    #pragma unroll 4
    for (int ci = 0; ci < CCH; ci += 4) {
        c0 = fmaf(srow[ci + 0], Wt[((ci + 0) << 8) + tid], c0);
        c1 = fmaf(srow[ci + 1], Wt[((ci + 1) << 8) + tid], c1);
        c2 = fmaf(srow[ci + 2], Wt[((ci + 2) << 8) + tid], c2);
        c3 = fmaf(srow[ci + 3], Wt[((ci + 3) << 8) + tid], c3);
    }
    rrow[tid] = ((c0 + c1) + (c2 + c3)) * (1.0f / 24.0f);
    __syncthreads();
    if (tid < 128) Eph[(size_t)blk * 128 + tid] = pk_bf16(rrow[2 * tid], rrow[2 * tid + 1]);
}

// ---------------- K4: out = H@E' + x, transposed write + BN partials ----------------
__global__ __launch_bounds__(256) void k_gather(const float* __restrict__ x,
                                                const unsigned int* __restrict__ idxu,
                                                const unsigned int* __restrict__ Eph,
                                                float* __restrict__ out,
                                                float* __restrict__ bn1,
                                                float* __restrict__ bn2) {
    __shared__ int   it[32 * KNN];          // 768 ints
    __shared__ float tile[32][CCH + 1];     // 32 x 257 = 32.9 KB
    int tid = threadIdx.x;
    int blk = blockIdx.x;                   // 2048: b * 512 node-chunks
    int b = blk >> 9;
    int n0 = (blk & 511) << 5;              // 32 nodes
    int cp = tid & 127, rs = tid >> 7;

    for (int i = tid; i < 32 * 12; i += 256) {           // 384 packed uints
        unsigned int u = idxu[(size_t)(b * NN + n0) * 12 + i];
        it[2 * i] = u & 0xFFFF;
        it[2 * i + 1] = u >> 16;
    }
    __syncthreads();

    const unsigned int* Eb = Eph + ((size_t)(b * MM) << 7);
    for (int j2 = 0; j2 < 16; ++j2) {
        int j = 2 * j2 + rs;
        int n = n0 + j;
        const int* itj = &it[j * KNN];
        float al = 0.f, ah = 0.f, bl = 0.f, bh = 0.f;
        float cl = 0.f, ch = 0.f, dl = 0.f, dh = 0.f;
        #pragma unroll
        for (int k = 0; k < KNN; k += 4) {
            unsigned int u0 = Eb[((size_t)itj[k + 0] << 7) + cp];
            unsigned int u1 = Eb[((size_t)itj[k + 1] << 7) + cp];
            unsigned int u2 = Eb[((size_t)itj[k + 2] << 7) + cp];
            unsigned int u3 = Eb[((size_t)itj[k + 3] << 7) + cp];
            al += lo_bf(u0); ah += hi_bf(u0);
            bl += lo_bf(u1); bh += hi_bf(u1);
            cl += lo_bf(u2); ch += hi_bf(u2);
            dl += lo_bf(u3); dh += hi_bf(u3);
        }
        float2 xv = ((const float2*)(x + (((size_t)(b * NN + n)) << 8)))[cp];
        tile[j][2 * cp + 0] = xv.x + ((al + bl) + (cl + dl));
        tile[j][2 * cp + 1] = xv.y + ((ah + bh) + (ch + dh));
    }
    __syncthreads();

    float sum = 0.f, ss = 0.f;
    #pragma unroll 4
    for (int j = 0; j < 32; ++j) {
        float v = tile[j][tid];
        sum += v; ss += v * v;
    }
    bn1[(size_t)blk * 256 + tid] = sum;
    bn2[(size_t)blk * 256 + tid] = ss;

    for (int i = tid; i < CCH * 32; i += 256) {
        int c2 = i >> 5, j2 = i & 31;
        out[(((size_t)(b * CCH + c2)) << 14) + n0 + j2] = tile[j2][c2];
    }
}

// ---------------- K5: finalize BN stats -> a[c], bb[c] ----------------
__global__ __launch_bounds__(256) void k_stats(const float* __restrict__ bn1,
                                               const float* __restrict__ bn2,
                                               const float* __restrict__ gamma,
                                               const float* __restrict__ beta,
                                               float* __restrict__ ab) {
    __shared__ float r1[256], r2[256];
    int c = blockIdx.x;
    int t = threadIdx.x;
    float s1 = 0.f, s2 = 0.f;
    for (int i = t; i < 2048; i += 256) {
        s1 += bn1[i * 256 + c];
        s2 += bn2[i * 256 + c];
    }
    r1[t] = s1; r2[t] = s2;
    __syncthreads();
    for (int o = 128; o > 0; o >>= 1) {
        if (t < o) { r1[t] += r1[t + o]; r2[t] += r2[t + o]; }
        __syncthreads();
    }
    if (t == 0) {
        float mean = r1[0] * (1.0f / 65536.0f);
        float var  = r2[0] * (1.0f / 65536.0f) - mean * mean;
        float istd = rsqrtf(var + EPSV);
        float a = gamma[c] * istd;
        ab[c] = a;
        ab[CCH + c] = beta[c] - mean * a;
    }
}

// ---------------- K6: in-place normalize + SiLU ----------------
__global__ __launch_bounds__(256) void k_silu(float* __restrict__ out,
                                              const float* __restrict__ ab) {
    int i = blockIdx.x * 256 + threadIdx.x;     // float4 index, 4194304 total
    int c = (i >> 12) & 255;
    float a = ab[c], bb = ab[CCH + c];
    float4 v = ((float4*)out)[i];
    float t0 = a * v.x + bb;
    float t1 = a * v.y + bb;
    float t2 = a * v.z + bb;
    float t3 = a * v.w + bb;
    v.x = t0 / (1.0f + __expf(-t0));
    v.y = t1 / (1.0f + __expf(-t1));
    v.z = t2 / (1.0f + __expf(-t2));
    v.w = t3 / (1.0f + __expf(-t3));
    ((float4*)out)[i] = v;
}

extern "C" void kernel_launch(void* const* d_in, const int* in_sizes, int n_in,
                              void* d_out, int out_size, void* d_ws, size_t ws_size,
                              hipStream_t stream) {
    (void)in_sizes; (void)n_in; (void)out_size; (void)ws_size;
    const float* x       = (const float*)d_in[0];
    const float* coords  = (const float*)d_in[1];
    const float* anchors = (const float*)d_in[2];
    const float* fcw     = (const float*)d_in[3];
    const float* fcb     = (const float*)d_in[4];
    const float* gamma   = (const float*)d_in[5];
    const float* beta    = (const float*)d_in[6];
    float* out = (float*)d_out;

    // bf16-packed x lives in d_out (33.5 MB of 67 MB); dead before k_gather
    // overwrites d_out. ws footprint 16.0 MB (< proven-safe 19.2 MB).
    unsigned int* xh = (unsigned int*)d_out;

    char* ws = (char*)d_ws;
    ushort_t*     ws_idx   = (ushort_t*)    (ws + 0);          // 3,145,728 B
    int*          ws_deg   = (int*)         (ws + 3145728);    //     8,192 B
    int*          ws_offs  = (int*)         (ws + 3153920);    //     8,192 B
    ushort_t*     ws_list  = (ushort_t*)    (ws + 3162112);    // 3,145,728 B
    int*          ws_histT = (int*)         (ws + 6307840);    // 2,097,152 B
    int*          ws_posT  = (int*)         (ws + 8404992);    // 2,097,152 B
    unsigned int* ws_eph   = (unsigned int*)(ws + 10502144);   // 1,048,576 B
    float*        ws_wt    = (float*)       (ws + 11550720);   //   262,144 B
    float*        ws_bn1   = (float*)       (ws + 11812864);   // 2,097,152 B
    float*        ws_bn2   = (float*)       (ws + 13910016);   // 2,097,152 B
    float*        ws_ab    = (float*)       (ws + 16007168);   //     2,048 B

    hipLaunchKernelGGL(k_cvt,     dim3(32768), dim3(256), 0, stream, x, xh);
    hipLaunchKernelGGL(k_wt,      dim3(256),   dim3(256), 0, stream, fcw, ws_wt);
    hipLaunchKernelGGL(k_topk,    dim3(1024),  dim3(128), 0, stream, coords, anchors, ws_idx, ws_histT);
    hipLaunchKernelGGL(k_scan,    dim3(2048),  dim3(64),  0, stream, ws_histT, ws_posT, ws_deg);
    hipLaunchKernelGGL(k_offsets, dim3(1),     dim3(256), 0, stream, ws_deg, ws_offs);
    hipLaunchKernelGGL(k_fill2,   dim3(1024),  dim3(256), 0, stream, (const unsigned int*)ws_idx, ws_posT, ws_offs, ws_list);
    hipLaunchKernelGGL(k_edge2,   dim3(2048),  dim3(256), 0, stream, xh, ws_list, ws_offs, ws_deg, ws_wt, fcb, ws_eph);
    hipLaunchKernelGGL(k_gather,  dim3(2048),  dim3(256), 0, stream, x, (const unsigned int*)ws_idx, ws_eph, out, ws_bn1, ws_bn2);
    hipLaunchKernelGGL(k_stats,   dim3(256),   dim3(256), 0, stream, ws_bn1, ws_bn2, gamma, beta, ws_ab);
    hipLaunchKernelGGL(k_silu,    dim3(16384), dim3(256), 0, stream, out, ws_ab);
}